// Round 3
// baseline (622.590 us; speedup 1.0000x reference)
//
#include <hip/hip_runtime.h>
#include <hip/hip_bf16.h>
#include <stdint.h>

// ---- problem constants ----
static constexpr int HW = 4096;     // 64*64
static constexpr int Cc = 256;
static constexpr int Gg = 32;
static constexpr float EPSV = 1e-6f;

typedef __attribute__((ext_vector_type(8))) short bf8_t;   // 8 bf16 (4 VGPR)
typedef __attribute__((ext_vector_type(4))) float f4_t;    // mfma acc

__device__ __forceinline__ ushort f2bf(float x) {
    union { float f; uint32_t u; } v; v.f = x;
    uint32_t r = v.u + 0x7FFFu + ((v.u >> 16) & 1u);
    return (ushort)(r >> 16);
}
__device__ __forceinline__ float bf2f(ushort u) {
    union { uint32_t u; float f; } v; v.u = ((uint32_t)u) << 16;
    return v.f;
}

// async global->LDS DMA, 16B per lane; lds dest is wave-uniform base (+lane*16 by HW)
__device__ __forceinline__ void gload16(const void* g, void* l) {
    __builtin_amdgcn_global_load_lds((const __attribute__((address_space(1))) void*)g,
                                     (__attribute__((address_space(3))) void*)l, 16, 0, 0);
}

// ---------------- weight convert + transpose: wT[which][d][c] = bf16(w[c][d]) ----------------
__global__ void wconv_kernel(const float* __restrict__ wq, const float* __restrict__ wk,
                             const float* __restrict__ wv, const float* __restrict__ wp,
                             ushort* __restrict__ wT) {
    const float* w = (blockIdx.y == 0) ? wq : (blockIdx.y == 1) ? wk : (blockIdx.y == 2) ? wv : wp;
    int idx = blockIdx.x * 256 + threadIdx.x;        // 65536 total
    int d = idx >> 8, c = idx & 255;
    wT[blockIdx.y * 65536 + d * 256 + c] = f2bf(w[c * 256 + d]);
}

// ---------------- GroupNorm ----------------
__global__ void gn_partial(const float* __restrict__ x, float* __restrict__ psum, float* __restrict__ psumsq) {
    int slice = blockIdx.x;   // 16
    int b = blockIdx.y;       // 8
    int c = threadIdx.x;      // 256
    const float* xp = x + ((size_t)b * HW + (size_t)slice * 256) * Cc + c;
    float s = 0.f, sq = 0.f;
    for (int p = 0; p < 256; ++p) { float v = xp[(size_t)p * Cc]; s += v; sq += v * v; }
    for (int m = 1; m < 8; m <<= 1) { s += __shfl_xor(s, m); sq += __shfl_xor(sq, m); }
    if ((c & 7) == 0) {
        int g = c >> 3;
        psum[(b * Gg + g) * 16 + slice] = s;
        psumsq[(b * Gg + g) * 16 + slice] = sq;
    }
}

__global__ void gn_stats(const float* __restrict__ psum, const float* __restrict__ psumsq,
                         float* __restrict__ stats) {
    int t = threadIdx.x;  // 256 = b*32+g
    float s = 0.f, sq = 0.f;
    for (int i = 0; i < 16; ++i) { s += psum[t * 16 + i]; sq += psumsq[t * 16 + i]; }
    float mean = s * (1.0f / 32768.0f);
    float var = sq * (1.0f / 32768.0f) - mean * mean;
    stats[t * 2] = mean;
    stats[t * 2 + 1] = rsqrtf(var + EPSV);
}

__global__ void gn_norm(const float* __restrict__ x, const float* __restrict__ stats,
                        const float* __restrict__ gs, const float* __restrict__ gb,
                        ushort* __restrict__ h) {
    size_t e = ((size_t)blockIdx.x * 256 + threadIdx.x) * 4;   // grid 8192
    int c = (int)(e & 255);
    int b = (int)(e >> 20);
    int g = c >> 3;
    float2 st = *(const float2*)&stats[(b * Gg + g) * 2];
    float4 v = *(const float4*)&x[e];
    float4 sc = *(const float4*)&gs[c];
    float4 bi = *(const float4*)&gb[c];
    ushort4 o;
    o.x = f2bf((v.x - st.x) * st.y * sc.x + bi.x);
    o.y = f2bf((v.y - st.x) * st.y * sc.y + bi.y);
    o.z = f2bf((v.z - st.x) * st.y * sc.z + bi.z);
    o.w = f2bf((v.w - st.x) * st.y * sc.w + bi.w);
    *(ushort4*)&h[e] = o;
}

// ---------------- QKV GEMM ----------------
// which==0: q (scaled by c^-0.5), which==1: k, which==2: V TRANSPOSED -> vT[b][d][hw]
__global__ __launch_bounds__(256) void qkv_gemm(const ushort* __restrict__ h, const ushort* __restrict__ wT,
                                                const float* __restrict__ bq, const float* __restrict__ bk,
                                                const float* __restrict__ bv,
                                                ushort* __restrict__ q, ushort* __restrict__ k,
                                                ushort* __restrict__ vT) {
    int which = blockIdx.y;
    const ushort* w = wT + which * 65536;
    const float* bias = which == 0 ? bq : which == 1 ? bk : bv;
    float scale = which == 0 ? 0.0625f : 1.0f;

    int lane = threadIdx.x & 63, wvi = threadIdx.x >> 6;
    int lq = lane & 15, lg = lane >> 4;
    int m0 = blockIdx.x * 64 + wvi * 16;

    bf8_t a[8];
    const ushort* arow = h + (size_t)(m0 + lq) * 256 + lg * 8;
#pragma unroll
    for (int ks = 0; ks < 8; ++ks) a[ks] = *(const bf8_t*)(arow + ks * 32);

    f4_t acc[16];
#pragma unroll
    for (int i = 0; i < 16; ++i) acc[i] = (f4_t)0.f;

    const ushort* brow = w + (size_t)lq * 256 + lg * 8;
#pragma unroll
    for (int nf = 0; nf < 16; ++nf) {
#pragma unroll
        for (int ks = 0; ks < 8; ++ks) {
            bf8_t bfr = *(const bf8_t*)(brow + nf * 16 * 256 + ks * 32);
            acc[nf] = __builtin_amdgcn_mfma_f32_16x16x32_bf16(a[ks], bfr, acc[nf], 0, 0, 0);
        }
    }
    if (which == 2) {
        int bt = m0 >> 12;
        int hw0 = (m0 & 4095) + lg * 4;
#pragma unroll
        for (int nf = 0; nf < 16; ++nf) {
            int col = nf * 16 + lq;
            float bsv = bias[col];
            ushort4 pk;
            pk.x = f2bf(acc[nf][0] + bsv);
            pk.y = f2bf(acc[nf][1] + bsv);
            pk.z = f2bf(acc[nf][2] + bsv);
            pk.w = f2bf(acc[nf][3] + bsv);
            *(ushort4*)&vT[(size_t)bt * (256 * 4096) + (size_t)col * 4096 + hw0] = pk;
        }
    } else {
        ushort* out = which == 0 ? q : k;
#pragma unroll
        for (int nf = 0; nf < 16; ++nf) {
            int col = nf * 16 + lq;
            float bsv = bias[col];
#pragma unroll
            for (int r = 0; r < 4; ++r) {
                int row = m0 + lg * 4 + r;
                out[(size_t)row * 256 + col] = f2bf((acc[nf][r] + bsv) * scale);
            }
        }
    }
}

// ---------------- flash attention, split-KV x2 ----------------
// 512 blocks: bid = batch + 8*half + 16*qt  (batch=bid&7 -> XCD pinning; all blocks on an
// XCD share one batch so K/V/vT stay in that XCD's L2). 4 waves x 32 q-rows = 128 q/block.
// Each block processes 32 of 64 kv-tiles. K double-buffered in LDS (2x32KB, DMA-staged,
// swizzled), V read directly from global vT (L1/L2-served), P per-wave LDS (4x4KB).
// LDS 80KB -> 2 blocks/CU -> 2 waves/SIMD. Defer-max skips O-rescale when max doesn't grow.
// Outputs: Opart[bid][128][256] bf16 (normalized by local l) + ml[bid][128] float2 (m, l).
__global__ __launch_bounds__(256, 2) void flash_kernel(const ushort* __restrict__ q,
                                                       const ushort* __restrict__ kk,
                                                       const ushort* __restrict__ vT,
                                                       ushort* __restrict__ Opart,
                                                       float* __restrict__ ml) {
    extern __shared__ char smem[];
    const int t = threadIdx.x, lane = t & 63, wvi = t >> 6;
    const int lq = lane & 15, lg = lane >> 4;
    const int bid = blockIdx.x;
    const int batch = bid & 7, half = (bid >> 3) & 1, qt = bid >> 4;
    const size_t bb = (size_t)batch * HW * Cc;
    const int t0 = half * 32;   // first kv tile

    // Q fragments for 2 q-subtiles
    const int qbase = qt * 128 + wvi * 32;
    bf8_t qf0[8], qf1[8];
    {
        const ushort* qr0 = q + bb + (size_t)(qbase + lq) * Cc + lg * 8;
        const ushort* qr1 = qr0 + 16 * Cc;
#pragma unroll
        for (int ks = 0; ks < 8; ++ks) {
            qf0[ks] = *(const bf8_t*)(qr0 + ks * 32);
            qf1[ks] = *(const bf8_t*)(qr1 + ks * 32);
        }
    }

    f4_t o0[16], o1[16];
#pragma unroll
    for (int i = 0; i < 16; ++i) { o0[i] = (f4_t)0.f; o1[i] = (f4_t)0.f; }
    float m0 = -1e30f, l0 = 0.f, m1 = -1e30f, l1 = 0.f;

    char* Pb = smem + 65536 + wvi * 4096;   // P0 at +0 (2KB), P1 at +2048

    const ushort* ksrc_b = kk + bb;
    const ushort* vsrc_b = vT + (size_t)batch * (256 * 4096);
    const int tb = wvi * 64;

    auto stage = [&](int kt, int bufsel) {
        const ushort* ks_ = ksrc_b + (size_t)kt * 64 * 256;
        char* kd = smem + bufsel * 32768;
        // K tile: 64 rows x 512B; LDS slot (kr, c') holds global chunk c = c' ^ (kr&7)
#pragma unroll
        for (int i = 0; i < 8; ++i) {
            int n = i * 256 + tb + lane;
            int kr = n >> 5;
            int c = (n & 31) ^ (kr & 7);
            gload16(ks_ + kr * 256 + c * 8, kd + (i * 256 + tb) * 16);
        }
    };

    stage(t0, 0);

    for (int it = 0; it < 32; ++it) {
        const int cur = it & 1;
        const int kt = t0 + it;
        if (it + 1 < 32) {
            stage(kt + 1, cur ^ 1);
            asm volatile("s_waitcnt vmcnt(8)" ::: "memory");   // current tile's 8 DMAs done
        } else {
            asm volatile("s_waitcnt vmcnt(0)" ::: "memory");
        }
        __builtin_amdgcn_s_barrier();
        __builtin_amdgcn_sched_barrier(0);

        const char* Kb = smem + cur * 32768;

        // QK^T (swapped): sa[mf][r] = S^T[k = mf*16+lg*4+r][q-col = lq]
        f4_t sa0[4], sa1[4];
#pragma unroll
        for (int mf = 0; mf < 4; ++mf) { sa0[mf] = (f4_t)0.f; sa1[mf] = (f4_t)0.f; }
#pragma unroll
        for (int ks = 0; ks < 8; ++ks) {
#pragma unroll
            for (int mf = 0; mf < 4; ++mf) {
                int kr = mf * 16 + lq;
                bf8_t kf = *(const bf8_t*)(Kb + kr * 512 + (((ks * 4 + lg) ^ (kr & 7)) * 16));
                sa0[mf] = __builtin_amdgcn_mfma_f32_16x16x32_bf16(kf, qf0[ks], sa0[mf], 0, 0, 0);
                sa1[mf] = __builtin_amdgcn_mfma_f32_16x16x32_bf16(kf, qf1[ks], sa1[mf], 0, 0, 0);
            }
        }

        // ---- online softmax with defer-max, qtile0 ----
        {
            float tmax = -1e30f;
#pragma unroll
            for (int mf = 0; mf < 4; ++mf)
#pragma unroll
                for (int r = 0; r < 4; ++r) tmax = fmaxf(tmax, sa0[mf][r]);
            tmax = fmaxf(tmax, __shfl_xor(tmax, 16));
            tmax = fmaxf(tmax, __shfl_xor(tmax, 32));
            if (!__all(tmax <= m0 + 6.0f)) {
                float mn = fmaxf(m0, tmax);
                float al = __expf(m0 - mn);
                l0 *= al; m0 = mn;
                float ar[4];
#pragma unroll
                for (int r = 0; r < 4; ++r) ar[r] = __shfl(al, lg * 4 + r);
#pragma unroll
                for (int nf = 0; nf < 16; ++nf)
#pragma unroll
                    for (int r = 0; r < 4; ++r) o0[nf][r] *= ar[r];
            }
            float ts = 0.f;
#pragma unroll
            for (int mf = 0; mf < 4; ++mf)
#pragma unroll
                for (int r = 0; r < 4; ++r) { float p = __expf(sa0[mf][r] - m0); sa0[mf][r] = p; ts += p; }
            ts += __shfl_xor(ts, 16);
            ts += __shfl_xor(ts, 32);
            l0 += ts;
#pragma unroll
            for (int mf = 0; mf < 4; ++mf)
#pragma unroll
                for (int rp = 0; rp < 2; ++rp) {
                    uint32_t pk = (uint32_t)f2bf(sa0[mf][rp * 2]) | ((uint32_t)f2bf(sa0[mf][rp * 2 + 1]) << 16);
                    int kx = mf * 16 + lg * 4 + rp * 2;
                    *(uint32_t*)(Pb + lq * 128 + (((kx >> 3) ^ (lq & 7)) * 16) + (kx & 7) * 2) = pk;
                }
        }
        // ---- online softmax with defer-max, qtile1 ----
        {
            float tmax = -1e30f;
#pragma unroll
            for (int mf = 0; mf < 4; ++mf)
#pragma unroll
                for (int r = 0; r < 4; ++r) tmax = fmaxf(tmax, sa1[mf][r]);
            tmax = fmaxf(tmax, __shfl_xor(tmax, 16));
            tmax = fmaxf(tmax, __shfl_xor(tmax, 32));
            if (!__all(tmax <= m1 + 6.0f)) {
                float mn = fmaxf(m1, tmax);
                float al = __expf(m1 - mn);
                l1 *= al; m1 = mn;
                float ar[4];
#pragma unroll
                for (int r = 0; r < 4; ++r) ar[r] = __shfl(al, lg * 4 + r);
#pragma unroll
                for (int nf = 0; nf < 16; ++nf)
#pragma unroll
                    for (int r = 0; r < 4; ++r) o1[nf][r] *= ar[r];
            }
            float ts = 0.f;
#pragma unroll
            for (int mf = 0; mf < 4; ++mf)
#pragma unroll
                for (int r = 0; r < 4; ++r) { float p = __expf(sa1[mf][r] - m1); sa1[mf][r] = p; ts += p; }
            ts += __shfl_xor(ts, 16);
            ts += __shfl_xor(ts, 32);
            l1 += ts;
#pragma unroll
            for (int mf = 0; mf < 4; ++mf)
#pragma unroll
                for (int rp = 0; rp < 2; ++rp) {
                    uint32_t pk = (uint32_t)f2bf(sa1[mf][rp * 2]) | ((uint32_t)f2bf(sa1[mf][rp * 2 + 1]) << 16);
                    int kx = mf * 16 + lg * 4 + rp * 2;
                    *(uint32_t*)(Pb + 2048 + lq * 128 + (((kx >> 3) ^ (lq & 7)) * 16) + (kx & 7) * 2) = pk;
                }
        }

        // PV: o += P @ V  (A = P from per-wave LDS, B = V fragments direct from global vT)
        const ushort* vt_ = vsrc_b + kt * 64;
#pragma unroll
        for (int ks2 = 0; ks2 < 2; ++ks2) {
            int chunk = ks2 * 4 + lg;
            bf8_t pf0 = *(const bf8_t*)(Pb + lq * 128 + ((chunk ^ (lq & 7)) * 16));
            bf8_t pf1 = *(const bf8_t*)(Pb + 2048 + lq * 128 + ((chunk ^ (lq & 7)) * 16));
#pragma unroll
            for (int nf = 0; nf < 16; ++nf) {
                int d = nf * 16 + lq;
                bf8_t vf = *(const bf8_t*)(vt_ + (size_t)d * HW + chunk * 8);
                o0[nf] = __builtin_amdgcn_mfma_f32_16x16x32_bf16(pf0, vf, o0[nf], 0, 0, 0);
                o1[nf] = __builtin_amdgcn_mfma_f32_16x16x32_bf16(pf1, vf, o1[nf], 0, 0, 0);
            }
        }
        __syncthreads();   // all reads of buf cur done before it is restaged next iter
    }

    // epilogue: normalize by local l, store bf16 partial + (m,l) per row
    float i0[4], i1[4];
#pragma unroll
    for (int r = 0; r < 4; ++r) {
        i0[r] = 1.0f / __shfl(l0, lg * 4 + r);
        i1[r] = 1.0f / __shfl(l1, lg * 4 + r);
    }
    ushort* op = Opart + (size_t)bid * (128 * 256) + (size_t)(wvi * 32) * 256;
#pragma unroll
    for (int nf = 0; nf < 16; ++nf) {
        int col = nf * 16 + lq;
#pragma unroll
        for (int r = 0; r < 4; ++r) {
            op[(size_t)(lg * 4 + r) * 256 + col] = f2bf(o0[nf][r] * i0[r]);
            op[(size_t)(16 + lg * 4 + r) * 256 + col] = f2bf(o1[nf][r] * i1[r]);
        }
    }
    if (lg == 0) {
        float2* mlp = (float2*)(ml + (size_t)(bid * 128 + wvi * 32) * 2);
        mlp[lq] = make_float2(m0, l0);
        mlp[16 + lq] = make_float2(m1, l1);
    }
}

// ---------------- combine split-KV partials -> h (bf16) ----------------
// 1024 blocks: pair = bid>>2 (256: batch=pair&7, qt=pair>>3), quarter = bid&3 (32 rows).
__global__ __launch_bounds__(256) void combine_kernel(const ushort* __restrict__ Opart,
                                                      const float* __restrict__ ml,
                                                      ushort* __restrict__ h) {
    int bid = blockIdx.x;
    int pair = bid >> 2, q4 = bid & 3;
    int batch = pair & 7, qt = pair >> 3;
    int blkA = batch + 16 * qt, blkB = blkA + 8;
    const ushort* A = Opart + (size_t)blkA * 32768;
    const ushort* B = Opart + (size_t)blkB * 32768;
    ushort* dst = h + (size_t)batch * HW * Cc + (size_t)qt * 128 * 256;
    int t = threadIdx.x;
#pragma unroll
    for (int it = 0; it < 4; ++it) {
        int idx = q4 * 8192 + it * 2048 + t * 8;
        int row = idx >> 8;
        float2 mla = *(const float2*)&ml[(blkA * 128 + row) * 2];
        float2 mlb = *(const float2*)&ml[(blkB * 128 + row) * 2];
        float M = fmaxf(mla.x, mlb.x);
        float ea = __expf(mla.x - M) * mla.y;
        float eb = __expf(mlb.x - M) * mlb.y;
        float inv = 1.0f / (ea + eb);
        float wa = ea * inv, wb = eb * inv;
        ushort4 a0 = *(const ushort4*)&A[idx], a1 = *(const ushort4*)&A[idx + 4];
        ushort4 b0 = *(const ushort4*)&B[idx], b1 = *(const ushort4*)&B[idx + 4];
        ushort4 r0, r1;
        r0.x = f2bf(bf2f(a0.x) * wa + bf2f(b0.x) * wb);
        r0.y = f2bf(bf2f(a0.y) * wa + bf2f(b0.y) * wb);
        r0.z = f2bf(bf2f(a0.z) * wa + bf2f(b0.z) * wb);
        r0.w = f2bf(bf2f(a0.w) * wa + bf2f(b0.w) * wb);
        r1.x = f2bf(bf2f(a1.x) * wa + bf2f(b1.x) * wb);
        r1.y = f2bf(bf2f(a1.y) * wa + bf2f(b1.y) * wb);
        r1.z = f2bf(bf2f(a1.z) * wa + bf2f(b1.z) * wb);
        r1.w = f2bf(bf2f(a1.w) * wa + bf2f(b1.w) * wb);
        *(ushort4*)&dst[idx] = r0;
        *(ushort4*)&dst[idx + 4] = r1;
    }
}

// ---------------- proj GEMM + bias + residual (fp32 out) ----------------
__global__ __launch_bounds__(256) void proj_gemm(const ushort* __restrict__ ao, const ushort* __restrict__ wT,
                                                 const float* __restrict__ bp, const float* __restrict__ x,
                                                 float* __restrict__ outp) {
    int lane = threadIdx.x & 63, wvi = threadIdx.x >> 6;
    int lq = lane & 15, lg = lane >> 4;
    int m0 = blockIdx.x * 64 + wvi * 16;

    bf8_t a[8];
    const ushort* arow = ao + (size_t)(m0 + lq) * 256 + lg * 8;
#pragma unroll
    for (int ks = 0; ks < 8; ++ks) a[ks] = *(const bf8_t*)(arow + ks * 32);

    f4_t acc[16];
#pragma unroll
    for (int i = 0; i < 16; ++i) acc[i] = (f4_t)0.f;

    const ushort* brow = wT + (size_t)lq * 256 + lg * 8;
#pragma unroll
    for (int nf = 0; nf < 16; ++nf) {
#pragma unroll
        for (int ks = 0; ks < 8; ++ks) {
            bf8_t bfr = *(const bf8_t*)(brow + nf * 16 * 256 + ks * 32);
            acc[nf] = __builtin_amdgcn_mfma_f32_16x16x32_bf16(a[ks], bfr, acc[nf], 0, 0, 0);
        }
    }
#pragma unroll
    for (int nf = 0; nf < 16; ++nf) {
        int col = nf * 16 + lq;
        float bsv = bp[col];
#pragma unroll
        for (int r = 0; r < 4; ++r) {
            size_t idx = (size_t)(m0 + lg * 4 + r) * 256 + col;
            outp[idx] = x[idx] + acc[nf][r] + bsv;
        }
    }
}

extern "C" void kernel_launch(void* const* d_in, const int* in_sizes, int n_in,
                              void* d_out, int out_size, void* d_ws, size_t ws_size,
                              hipStream_t stream) {
    const float* x  = (const float*)d_in[0];
    const float* gs = (const float*)d_in[1];
    const float* gb = (const float*)d_in[2];
    const float* wq = (const float*)d_in[3];
    const float* bq = (const float*)d_in[4];
    const float* wk = (const float*)d_in[5];
    const float* bk = (const float*)d_in[6];
    const float* wv = (const float*)d_in[7];
    const float* bv = (const float*)d_in[8];
    const float* wp = (const float*)d_in[9];
    const float* bp = (const float*)d_in[10];
    float* out = (float*)d_out;

    char* ws = (char*)d_ws;
    ushort* wT    = (ushort*)ws;                         // 512 KB
    float*  psum  = (float*)(ws + 512 * 1024);
    float*  psumsq= (float*)(ws + 528 * 1024);
    float*  stats = (float*)(ws + 544 * 1024);
    ushort* h     = (ushort*)(ws + (1 << 20));           // 16 MB (reused as attn out)
    ushort* qb    = (ushort*)(ws + (size_t)17 * (1 << 20));
    ushort* kb    = (ushort*)(ws + (size_t)33 * (1 << 20));
    ushort* vTb   = (ushort*)(ws + (size_t)49 * (1 << 20));   // V transposed [b][d][hw]
    ushort* Opart = (ushort*)(ws + (size_t)65 * (1 << 20));   // 32 MB: 512 x 128 x 256 bf16
    float*  mlb   = (float*)(ws + (size_t)97 * (1 << 20));    // 512 KB: 512 x 128 x float2

    wconv_kernel<<<dim3(256, 4), 256, 0, stream>>>(wq, wk, wv, wp, wT);
    gn_partial<<<dim3(16, 8), 256, 0, stream>>>(x, psum, psumsq);
    gn_stats<<<1, 256, 0, stream>>>(psum, psumsq, stats);
    gn_norm<<<8192, 256, 0, stream>>>(x, stats, gs, gb, h);
    qkv_gemm<<<dim3(512, 3), 256, 0, stream>>>(h, wT, bq, bk, bv, qb, kb, vTb);

    hipFuncSetAttribute(reinterpret_cast<const void*>(flash_kernel),
                        hipFuncAttributeMaxDynamicSharedMemorySize, 81920);
    flash_kernel<<<512, 256, 81920, stream>>>(qb, kb, vTb, Opart, mlb);
    combine_kernel<<<1024, 256, 0, stream>>>(Opart, mlb, h);

    proj_gemm<<<512, 256, 0, stream>>>(h, wT + 3 * 65536, bp, x, out);
}

// Round 5
// 375.194 us; speedup vs baseline: 1.6594x; 1.6594x over previous
//
#include <hip/hip_runtime.h>
#include <hip/hip_bf16.h>
#include <stdint.h>

// ---- problem constants ----
static constexpr int HW = 4096;     // 64*64
static constexpr int Cc = 256;
static constexpr int Gg = 32;
static constexpr float EPSV = 1e-6f;

typedef __attribute__((ext_vector_type(8))) short bf8_t;   // 8 bf16 (4 VGPR)
typedef __attribute__((ext_vector_type(4))) float f4_t;    // mfma acc

__device__ __forceinline__ ushort f2bf(float x) {
    union { float f; uint32_t u; } v; v.f = x;
    uint32_t r = v.u + 0x7FFFu + ((v.u >> 16) & 1u);
    return (ushort)(r >> 16);
}
__device__ __forceinline__ float bf2f(ushort u) {
    union { uint32_t u; float f; } v; v.u = ((uint32_t)u) << 16;
    return v.f;
}

// async global->LDS DMA, 16B per lane; lds dest is wave-uniform base (+lane*16 by HW)
__device__ __forceinline__ void gload16(const void* g, void* l) {
    __builtin_amdgcn_global_load_lds((const __attribute__((address_space(1))) void*)g,
                                     (__attribute__((address_space(3))) void*)l, 16, 0, 0);
}

// ---------------- weight convert + transpose: wT[which][d][c] = bf16(w[c][d]) ----------------
__global__ void wconv_kernel(const float* __restrict__ wq, const float* __restrict__ wk,
                             const float* __restrict__ wv, const float* __restrict__ wp,
                             ushort* __restrict__ wT) {
    const float* w = (blockIdx.y == 0) ? wq : (blockIdx.y == 1) ? wk : (blockIdx.y == 2) ? wv : wp;
    int idx = blockIdx.x * 256 + threadIdx.x;        // 65536 total
    int d = idx >> 8, c = idx & 255;
    wT[blockIdx.y * 65536 + d * 256 + c] = f2bf(w[c * 256 + d]);
}

// ---------------- GroupNorm ----------------
// pass 1: per (b, slice of 64 pixels) partial sums per group. grid (64, 8) = full GPU.
__global__ void gn_partial(const float* __restrict__ x, float* __restrict__ psum, float* __restrict__ psumsq) {
    int slice = blockIdx.x;   // 64
    int b = blockIdx.y;       // 8
    int c = threadIdx.x;      // 256
    const float* xp = x + ((size_t)b * HW + (size_t)slice * 64) * Cc + c;
    float s = 0.f, sq = 0.f;
    for (int p = 0; p < 64; ++p) { float v = xp[(size_t)p * Cc]; s += v; sq += v * v; }
    for (int m = 1; m < 8; m <<= 1) { s += __shfl_xor(s, m); sq += __shfl_xor(sq, m); }
    if ((c & 7) == 0) {
        int g = c >> 3;
        psum[(b * Gg + g) * 64 + slice] = s;
        psumsq[(b * Gg + g) * 64 + slice] = sq;
    }
}

__global__ void gn_stats(const float* __restrict__ psum, const float* __restrict__ psumsq,
                         float* __restrict__ stats) {
    int t = threadIdx.x;  // 256 = b*32+g
    float s = 0.f, sq = 0.f;
    for (int i = 0; i < 64; ++i) { s += psum[t * 64 + i]; sq += psumsq[t * 64 + i]; }
    float mean = s * (1.0f / 32768.0f);
    float var = sq * (1.0f / 32768.0f) - mean * mean;
    stats[t * 2] = mean;
    stats[t * 2 + 1] = rsqrtf(var + EPSV);
}

__global__ void gn_norm(const float* __restrict__ x, const float* __restrict__ stats,
                        const float* __restrict__ gs, const float* __restrict__ gb,
                        ushort* __restrict__ h) {
    size_t e = ((size_t)blockIdx.x * 256 + threadIdx.x) * 4;   // grid 8192
    int c = (int)(e & 255);
    int b = (int)(e >> 20);
    int g = c >> 3;
    float2 st = *(const float2*)&stats[(b * Gg + g) * 2];
    float4 v = *(const float4*)&x[e];
    float4 sc = *(const float4*)&gs[c];
    float4 bi = *(const float4*)&gb[c];
    ushort4 o;
    o.x = f2bf((v.x - st.x) * st.y * sc.x + bi.x);
    o.y = f2bf((v.y - st.x) * st.y * sc.y + bi.y);
    o.z = f2bf((v.z - st.x) * st.y * sc.z + bi.z);
    o.w = f2bf((v.w - st.x) * st.y * sc.w + bi.w);
    *(ushort4*)&h[e] = o;
}

// ---------------- QKV GEMM ----------------
// which==0: q (scaled by c^-0.5), which==1: k, which==2: V TRANSPOSED -> vT[b][d][hw]
__global__ __launch_bounds__(256) void qkv_gemm(const ushort* __restrict__ h, const ushort* __restrict__ wT,
                                                const float* __restrict__ bq, const float* __restrict__ bk,
                                                const float* __restrict__ bv,
                                                ushort* __restrict__ q, ushort* __restrict__ k,
                                                ushort* __restrict__ vT) {
    int which = blockIdx.y;
    const ushort* w = wT + which * 65536;
    const float* bias = which == 0 ? bq : which == 1 ? bk : bv;
    float scale = which == 0 ? 0.0625f : 1.0f;

    int lane = threadIdx.x & 63, wvi = threadIdx.x >> 6;
    int lq = lane & 15, lg = lane >> 4;
    int m0 = blockIdx.x * 64 + wvi * 16;

    bf8_t a[8];
    const ushort* arow = h + (size_t)(m0 + lq) * 256 + lg * 8;
#pragma unroll
    for (int ks = 0; ks < 8; ++ks) a[ks] = *(const bf8_t*)(arow + ks * 32);

    f4_t acc[16];
#pragma unroll
    for (int i = 0; i < 16; ++i) acc[i] = (f4_t)0.f;

    const ushort* brow = w + (size_t)lq * 256 + lg * 8;
#pragma unroll
    for (int nf = 0; nf < 16; ++nf) {
#pragma unroll
        for (int ks = 0; ks < 8; ++ks) {
            bf8_t bfr = *(const bf8_t*)(brow + nf * 16 * 256 + ks * 32);
            acc[nf] = __builtin_amdgcn_mfma_f32_16x16x32_bf16(a[ks], bfr, acc[nf], 0, 0, 0);
        }
    }
    if (which == 2) {
        int bt = m0 >> 12;
        int hw0 = (m0 & 4095) + lg * 4;
#pragma unroll
        for (int nf = 0; nf < 16; ++nf) {
            int col = nf * 16 + lq;
            float bsv = bias[col];
            ushort4 pk;
            pk.x = f2bf(acc[nf][0] + bsv);
            pk.y = f2bf(acc[nf][1] + bsv);
            pk.z = f2bf(acc[nf][2] + bsv);
            pk.w = f2bf(acc[nf][3] + bsv);
            *(ushort4*)&vT[(size_t)bt * (256 * 4096) + (size_t)col * 4096 + hw0] = pk;
        }
    } else {
        ushort* out = which == 0 ? q : k;
#pragma unroll
        for (int nf = 0; nf < 16; ++nf) {
            int col = nf * 16 + lq;
            float bsv = bias[col];
#pragma unroll
            for (int r = 0; r < 4; ++r) {
                int row = m0 + lg * 4 + r;
                out[(size_t)row * 256 + col] = f2bf((acc[nf][r] + bsv) * scale);
            }
        }
    }
}

// ---------------- flash attention, split-KV x2, 8 waves, 160KB LDS ----------------
// 256 blocks: batch=bid&7 (XCD pinning), half=(bid>>3)&1, qt=bid>>4 (0..15). 8 waves x
// 32 q-rows = 256 q-rows/block; each block does 32 of 64 kv-tiles. K dbuf 2x32KB + Vt
// dbuf 2x32KB staged via global_load_lds (swizzled src); P per-wave 8x4KB. LDS=160KB ->
// 1 block/CU = 8 waves = 2 waves/SIMD (softmax of one wave overlaps MFMA of the other).
__global__ __launch_bounds__(512, 2) void flash_kernel(const ushort* __restrict__ q,
                                                       const ushort* __restrict__ kk,
                                                       const ushort* __restrict__ vT,
                                                       ushort* __restrict__ Opart,
                                                       float* __restrict__ ml) {
    extern __shared__ char smem[];
    const int t = threadIdx.x, lane = t & 63, wvi = t >> 6;
    const int lq = lane & 15, lg = lane >> 4;
    const int bid = blockIdx.x;
    const int batch = bid & 7, half = (bid >> 3) & 1, qt = bid >> 4;
    const size_t bb = (size_t)batch * HW * Cc;
    const int t0 = half * 32;   // first kv tile

    // Q fragments for 2 q-subtiles (wave owns rows qbase..qbase+31)
    const int qbase = qt * 256 + wvi * 32;
    bf8_t qf0[8], qf1[8];
    {
        const ushort* qr0 = q + bb + (size_t)(qbase + lq) * Cc + lg * 8;
        const ushort* qr1 = qr0 + 16 * Cc;
#pragma unroll
        for (int ks = 0; ks < 8; ++ks) {
            qf0[ks] = *(const bf8_t*)(qr0 + ks * 32);
            qf1[ks] = *(const bf8_t*)(qr1 + ks * 32);
        }
    }

    f4_t o0[16], o1[16];
#pragma unroll
    for (int i = 0; i < 16; ++i) { o0[i] = (f4_t)0.f; o1[i] = (f4_t)0.f; }
    float m0 = -1e30f, l0 = 0.f, m1 = -1e30f, l1 = 0.f;

    char* Pb = smem + 131072 + wvi * 4096;   // P0 at +0 (2KB), P1 at +2048

    const ushort* ksrc_b = kk + bb;
    const ushort* vsrc_b = vT + (size_t)batch * (256 * 4096);
    const int tb = wvi * 64;

    auto stage = [&](int kt, int bufsel) {
        const ushort* ks_ = ksrc_b + (size_t)kt * 64 * 256;
        const ushort* vs_ = vsrc_b + kt * 64;
        char* kd = smem + bufsel * 32768;
        char* vd = smem + 65536 + bufsel * 32768;
        // K tile: 64 rows x 512B; LDS slot (kr, c') holds global chunk c = c' ^ (kr&7)
#pragma unroll
        for (int i = 0; i < 4; ++i) {
            int n = i * 512 + tb + lane;
            int kr = n >> 5;
            int c = (n & 31) ^ (kr & 7);
            gload16(ks_ + kr * 256 + c * 8, kd + (i * 512 + tb) * 16);
        }
        // Vt tile: 256 rows x 128B; slot (d, c') holds chunk c = c' ^ (d&7)
#pragma unroll
        for (int i = 0; i < 4; ++i) {
            int n = i * 512 + tb + lane;
            int d = n >> 3;
            int c = (n & 7) ^ (d & 7);
            gload16(vs_ + (size_t)d * HW + c * 8, vd + (i * 512 + tb) * 16);
        }
    };

    stage(t0, 0);

    for (int it = 0; it < 32; ++it) {
        const int cur = it & 1;
        const int kt = t0 + it;
        if (it + 1 < 32) {
            stage(kt + 1, cur ^ 1);
            asm volatile("s_waitcnt vmcnt(8)" ::: "memory");   // current tile's 8 DMAs done
        } else {
            asm volatile("s_waitcnt vmcnt(0)" ::: "memory");
        }
        __builtin_amdgcn_s_barrier();
        __builtin_amdgcn_sched_barrier(0);

        const char* Kb = smem + cur * 32768;
        const char* Vb = smem + 65536 + cur * 32768;

        // QK^T (swapped): sa[mf][r] = S^T[k = mf*16+lg*4+r][q-col = lq]
        f4_t sa0[4], sa1[4];
#pragma unroll
        for (int mf = 0; mf < 4; ++mf) { sa0[mf] = (f4_t)0.f; sa1[mf] = (f4_t)0.f; }
        __builtin_amdgcn_s_setprio(1);
#pragma unroll
        for (int ks = 0; ks < 8; ++ks) {
#pragma unroll
            for (int mf = 0; mf < 4; ++mf) {
                int kr = mf * 16 + lq;
                bf8_t kf = *(const bf8_t*)(Kb + kr * 512 + (((ks * 4 + lg) ^ (kr & 7)) * 16));
                sa0[mf] = __builtin_amdgcn_mfma_f32_16x16x32_bf16(kf, qf0[ks], sa0[mf], 0, 0, 0);
                sa1[mf] = __builtin_amdgcn_mfma_f32_16x16x32_bf16(kf, qf1[ks], sa1[mf], 0, 0, 0);
            }
        }
        __builtin_amdgcn_s_setprio(0);

        // ---- online softmax with defer-max, qtile0 ----
        {
            float tmax = -1e30f;
#pragma unroll
            for (int mf = 0; mf < 4; ++mf)
#pragma unroll
                for (int r = 0; r < 4; ++r) tmax = fmaxf(tmax, sa0[mf][r]);
            tmax = fmaxf(tmax, __shfl_xor(tmax, 16));
            tmax = fmaxf(tmax, __shfl_xor(tmax, 32));
            if (!__all(tmax <= m0 + 6.0f)) {
                float mn = fmaxf(m0, tmax);
                float al = __expf(m0 - mn);
                l0 *= al; m0 = mn;
                float ar[4];
#pragma unroll
                for (int r = 0; r < 4; ++r) ar[r] = __shfl(al, lg * 4 + r);
#pragma unroll
                for (int nf = 0; nf < 16; ++nf)
#pragma unroll
                    for (int r = 0; r < 4; ++r) o0[nf][r] *= ar[r];
            }
            float ts = 0.f;
#pragma unroll
            for (int mf = 0; mf < 4; ++mf)
#pragma unroll
                for (int r = 0; r < 4; ++r) { float p = __expf(sa0[mf][r] - m0); sa0[mf][r] = p; ts += p; }
            ts += __shfl_xor(ts, 16);
            ts += __shfl_xor(ts, 32);
            l0 += ts;
#pragma unroll
            for (int mf = 0; mf < 4; ++mf)
#pragma unroll
                for (int rp = 0; rp < 2; ++rp) {
                    uint32_t pk = (uint32_t)f2bf(sa0[mf][rp * 2]) | ((uint32_t)f2bf(sa0[mf][rp * 2 + 1]) << 16);
                    int kx = mf * 16 + lg * 4 + rp * 2;
                    *(uint32_t*)(Pb + lq * 128 + (((kx >> 3) ^ (lq & 7)) * 16) + (kx & 7) * 2) = pk;
                }
        }
        // ---- online softmax with defer-max, qtile1 ----
        {
            float tmax = -1e30f;
#pragma unroll
            for (int mf = 0; mf < 4; ++mf)
#pragma unroll
                for (int r = 0; r < 4; ++r) tmax = fmaxf(tmax, sa1[mf][r]);
            tmax = fmaxf(tmax, __shfl_xor(tmax, 16));
            tmax = fmaxf(tmax, __shfl_xor(tmax, 32));
            if (!__all(tmax <= m1 + 6.0f)) {
                float mn = fmaxf(m1, tmax);
                float al = __expf(m1 - mn);
                l1 *= al; m1 = mn;
                float ar[4];
#pragma unroll
                for (int r = 0; r < 4; ++r) ar[r] = __shfl(al, lg * 4 + r);
#pragma unroll
                for (int nf = 0; nf < 16; ++nf)
#pragma unroll
                    for (int r = 0; r < 4; ++r) o1[nf][r] *= ar[r];
            }
            float ts = 0.f;
#pragma unroll
            for (int mf = 0; mf < 4; ++mf)
#pragma unroll
                for (int r = 0; r < 4; ++r) { float p = __expf(sa1[mf][r] - m1); sa1[mf][r] = p; ts += p; }
            ts += __shfl_xor(ts, 16);
            ts += __shfl_xor(ts, 32);
            l1 += ts;
#pragma unroll
            for (int mf = 0; mf < 4; ++mf)
#pragma unroll
                for (int rp = 0; rp < 2; ++rp) {
                    uint32_t pk = (uint32_t)f2bf(sa1[mf][rp * 2]) | ((uint32_t)f2bf(sa1[mf][rp * 2 + 1]) << 16);
                    int kx = mf * 16 + lg * 4 + rp * 2;
                    *(uint32_t*)(Pb + 2048 + lq * 128 + (((kx >> 3) ^ (lq & 7)) * 16) + (kx & 7) * 2) = pk;
                }
        }

        // PV: o += P @ V  (A = P from per-wave LDS, B = Vt fragments from LDS, shared)
        __builtin_amdgcn_s_setprio(1);
#pragma unroll
        for (int ks2 = 0; ks2 < 2; ++ks2) {
            int chunk = ks2 * 4 + lg;
            bf8_t pf0 = *(const bf8_t*)(Pb + lq * 128 + ((chunk ^ (lq & 7)) * 16));
            bf8_t pf1 = *(const bf8_t*)(Pb + 2048 + lq * 128 + ((chunk ^ (lq & 7)) * 16));
#pragma unroll
            for (int nf = 0; nf < 16; ++nf) {
                int d = nf * 16 + lq;
                bf8_t vf = *(const bf8_t*)(Vb + d * 128 + ((chunk ^ (d & 7)) * 16));
                o0[nf] = __builtin_amdgcn_mfma_f32_16x16x32_bf16(pf0, vf, o0[nf], 0, 0, 0);
                o1[nf] = __builtin_amdgcn_mfma_f32_16x16x32_bf16(pf1, vf, o1[nf], 0, 0, 0);
            }
        }
        __builtin_amdgcn_s_setprio(0);
        __syncthreads();   // all reads of buf cur done before it is restaged next iter
    }

    // epilogue: normalize by local l, store bf16 partial + (m,l) per row
    float i0[4], i1[4];
#pragma unroll
    for (int r = 0; r < 4; ++r) {
        i0[r] = 1.0f / __shfl(l0, lg * 4 + r);
        i1[r] = 1.0f / __shfl(l1, lg * 4 + r);
    }
    ushort* op = Opart + (size_t)bid * (256 * 256) + (size_t)(wvi * 32) * 256;
#pragma unroll
    for (int nf = 0; nf < 16; ++nf) {
        int col = nf * 16 + lq;
#pragma unroll
        for (int r = 0; r < 4; ++r) {
            op[(size_t)(lg * 4 + r) * 256 + col] = f2bf(o0[nf][r] * i0[r]);
            op[(size_t)(16 + lg * 4 + r) * 256 + col] = f2bf(o1[nf][r] * i1[r]);
        }
    }
    if (lg == 0) {
        float2* mlp = (float2*)(ml + (size_t)(bid * 256 + wvi * 32) * 2);
        mlp[lq] = make_float2(m0, l0);
        mlp[16 + lq] = make_float2(m1, l1);
    }
}

// ---------------- combine split-KV partials -> h (bf16) ----------------
// 1024 blocks: pair = bid>>3 (128: batch=pair&7, qt=pair>>3 in 0..15), q8 = bid&7
// (32 rows each of the 256-row q-tile).
__global__ __launch_bounds__(256) void combine_kernel(const ushort* __restrict__ Opart,
                                                      const float* __restrict__ ml,
                                                      ushort* __restrict__ h) {
    int bid = blockIdx.x;
    int pair = bid >> 3, q8 = bid & 7;
    int batch = pair & 7, qt = pair >> 3;
    int blkA = batch + 16 * qt, blkB = blkA + 8;
    const ushort* A = Opart + (size_t)blkA * 65536;
    const ushort* B = Opart + (size_t)blkB * 65536;
    ushort* dst = h + (size_t)batch * HW * Cc + (size_t)qt * 256 * 256;
    int t = threadIdx.x;
#pragma unroll
    for (int it = 0; it < 4; ++it) {
        int idx = q8 * 8192 + it * 2048 + t * 8;
        int row = idx >> 8;
        float2 mla = *(const float2*)&ml[(blkA * 256 + row) * 2];
        float2 mlb = *(const float2*)&ml[(blkB * 256 + row) * 2];
        float M = fmaxf(mla.x, mlb.x);
        float ea = __expf(mla.x - M) * mla.y;
        float eb = __expf(mlb.x - M) * mlb.y;
        float inv = 1.0f / (ea + eb);
        float wa = ea * inv, wb = eb * inv;
        ushort4 a0 = *(const ushort4*)&A[idx], a1 = *(const ushort4*)&A[idx + 4];
        ushort4 b0 = *(const ushort4*)&B[idx], b1 = *(const ushort4*)&B[idx + 4];
        ushort4 r0, r1;
        r0.x = f2bf(bf2f(a0.x) * wa + bf2f(b0.x) * wb);
        r0.y = f2bf(bf2f(a0.y) * wa + bf2f(b0.y) * wb);
        r0.z = f2bf(bf2f(a0.z) * wa + bf2f(b0.z) * wb);
        r0.w = f2bf(bf2f(a0.w) * wa + bf2f(b0.w) * wb);
        r1.x = f2bf(bf2f(a1.x) * wa + bf2f(b1.x) * wb);
        r1.y = f2bf(bf2f(a1.y) * wa + bf2f(b1.y) * wb);
        r1.z = f2bf(bf2f(a1.z) * wa + bf2f(b1.z) * wb);
        r1.w = f2bf(bf2f(a1.w) * wa + bf2f(b1.w) * wb);
        *(ushort4*)&dst[idx] = r0;
        *(ushort4*)&dst[idx + 4] = r1;
    }
}

// ---------------- proj GEMM + bias + residual (fp32 out) ----------------
__global__ __launch_bounds__(256) void proj_gemm(const ushort* __restrict__ ao, const ushort* __restrict__ wT,
                                                 const float* __restrict__ bp, const float* __restrict__ x,
                                                 float* __restrict__ outp) {
    int lane = threadIdx.x & 63, wvi = threadIdx.x >> 6;
    int lq = lane & 15, lg = lane >> 4;
    int m0 = blockIdx.x * 64 + wvi * 16;

    bf8_t a[8];
    const ushort* arow = ao + (size_t)(m0 + lq) * 256 + lg * 8;
#pragma unroll
    for (int ks = 0; ks < 8; ++ks) a[ks] = *(const bf8_t*)(arow + ks * 32);

    f4_t acc[16];
#pragma unroll
    for (int i = 0; i < 16; ++i) acc[i] = (f4_t)0.f;

    const ushort* brow = wT + (size_t)lq * 256 + lg * 8;
#pragma unroll
    for (int nf = 0; nf < 16; ++nf) {
#pragma unroll
        for (int ks = 0; ks < 8; ++ks) {
            bf8_t bfr = *(const bf8_t*)(brow + nf * 16 * 256 + ks * 32);
            acc[nf] = __builtin_amdgcn_mfma_f32_16x16x32_bf16(a[ks], bfr, acc[nf], 0, 0, 0);
        }
    }
#pragma unroll
    for (int nf = 0; nf < 16; ++nf) {
        int col = nf * 16 + lq;
        float bsv = bp[col];
#pragma unroll
        for (int r = 0; r < 4; ++r) {
            size_t idx = (size_t)(m0 + lg * 4 + r) * 256 + col;
            outp[idx] = x[idx] + acc[nf][r] + bsv;
        }
    }
}

extern "C" void kernel_launch(void* const* d_in, const int* in_sizes, int n_in,
                              void* d_out, int out_size, void* d_ws, size_t ws_size,
                              hipStream_t stream) {
    const float* x  = (const float*)d_in[0];
    const float* gs = (const float*)d_in[1];
    const float* gb = (const float*)d_in[2];
    const float* wq = (const float*)d_in[3];
    const float* bq = (const float*)d_in[4];
    const float* wk = (const float*)d_in[5];
    const float* bk = (const float*)d_in[6];
    const float* wv = (const float*)d_in[7];
    const float* bv = (const float*)d_in[8];
    const float* wp = (const float*)d_in[9];
    const float* bp = (const float*)d_in[10];
    float* out = (float*)d_out;

    char* ws = (char*)d_ws;
    ushort* wT    = (ushort*)ws;                         // 512 KB
    float*  psum  = (float*)(ws + 512 * 1024);           // 64 KB
    float*  psumsq= (float*)(ws + 576 * 1024);           // 64 KB
    float*  stats = (float*)(ws + 640 * 1024);           // 2 KB
    ushort* h     = (ushort*)(ws + (1 << 20));           // 16 MB (reused as attn out)
    ushort* qb    = (ushort*)(ws + (size_t)17 * (1 << 20));
    ushort* kb    = (ushort*)(ws + (size_t)33 * (1 << 20));
    ushort* vTb   = (ushort*)(ws + (size_t)49 * (1 << 20));   // V transposed [b][d][hw]
    ushort* Opart = (ushort*)(ws + (size_t)65 * (1 << 20));   // 32 MB: 256 x 256 x 256 bf16
    float*  mlb   = (float*)(ws + (size_t)97 * (1 << 20));    // 512 KB: 256 x 256 x float2

    wconv_kernel<<<dim3(256, 4), 256, 0, stream>>>(wq, wk, wv, wp, wT);
    gn_partial<<<dim3(64, 8), 256, 0, stream>>>(x, psum, psumsq);
    gn_stats<<<1, 256, 0, stream>>>(psum, psumsq, stats);
    gn_norm<<<8192, 256, 0, stream>>>(x, stats, gs, gb, h);
    qkv_gemm<<<dim3(512, 3), 256, 0, stream>>>(h, wT, bq, bk, bv, qb, kb, vTb);

    hipFuncSetAttribute(reinterpret_cast<const void*>(flash_kernel),
                        hipFuncAttributeMaxDynamicSharedMemorySize, 163840);
    flash_kernel<<<256, 512, 163840, stream>>>(qb, kb, vTb, Opart, mlb);
    combine_kernel<<<1024, 256, 0, stream>>>(Opart, mlb, h);

    proj_gemm<<<512, 256, 0, stream>>>(h, wT + 3 * 65536, bp, x, out);
}

// Round 6
// 366.042 us; speedup vs baseline: 1.7009x; 1.0250x over previous
//
#include <hip/hip_runtime.h>
#include <hip/hip_bf16.h>
#include <stdint.h>

// ---- problem constants ----
static constexpr int HW = 4096;     // 64*64
static constexpr int Cc = 256;
static constexpr int Gg = 32;
static constexpr float EPSV = 1e-6f;
static constexpr float QSCALE = 0.0625f * 1.44269504f;   // c^-0.5 * log2(e): softmax in exp2 domain

typedef __attribute__((ext_vector_type(8))) short bf8_t;   // 8 bf16 (4 VGPR)
typedef __attribute__((ext_vector_type(4))) float f4_t;    // mfma acc

__device__ __forceinline__ ushort f2bf(float x) {
    union { float f; uint32_t u; } v; v.f = x;
    uint32_t r = v.u + 0x7FFFu + ((v.u >> 16) & 1u);
    return (ushort)(r >> 16);
}
__device__ __forceinline__ float bf2f(ushort u) {
    union { uint32_t u; float f; } v; v.u = ((uint32_t)u) << 16;
    return v.f;
}

// async global->LDS DMA, 16B per lane; lds dest is wave-uniform base (+lane*16 by HW)
__device__ __forceinline__ void gload16(const void* g, void* l) {
    __builtin_amdgcn_global_load_lds((const __attribute__((address_space(1))) void*)g,
                                     (__attribute__((address_space(3))) void*)l, 16, 0, 0);
}

// ---------------- weight convert + transpose: wT[which][d][c] = bf16(w[c][d]) ----------------
__global__ void wconv_kernel(const float* __restrict__ wq, const float* __restrict__ wk,
                             const float* __restrict__ wv, const float* __restrict__ wp,
                             ushort* __restrict__ wT) {
    const float* w = (blockIdx.y == 0) ? wq : (blockIdx.y == 1) ? wk : (blockIdx.y == 2) ? wv : wp;
    int idx = blockIdx.x * 256 + threadIdx.x;        // 65536 total
    int d = idx >> 8, c = idx & 255;
    wT[blockIdx.y * 65536 + d * 256 + c] = f2bf(w[c * 256 + d]);
}

// ---------------- GroupNorm ----------------
__global__ void gn_partial(const float* __restrict__ x, float* __restrict__ psum, float* __restrict__ psumsq) {
    int slice = blockIdx.x;   // 64
    int b = blockIdx.y;       // 8
    int c = threadIdx.x;      // 256
    const float* xp = x + ((size_t)b * HW + (size_t)slice * 64) * Cc + c;
    float s = 0.f, sq = 0.f;
    for (int p = 0; p < 64; ++p) { float v = xp[(size_t)p * Cc]; s += v; sq += v * v; }
    for (int m = 1; m < 8; m <<= 1) { s += __shfl_xor(s, m); sq += __shfl_xor(sq, m); }
    if ((c & 7) == 0) {
        int g = c >> 3;
        psum[(b * Gg + g) * 64 + slice] = s;
        psumsq[(b * Gg + g) * 64 + slice] = sq;
    }
}

__global__ void gn_stats(const float* __restrict__ psum, const float* __restrict__ psumsq,
                         float* __restrict__ stats) {
    int t = threadIdx.x;  // 256 = b*32+g
    float s = 0.f, sq = 0.f;
    for (int i = 0; i < 64; ++i) { s += psum[t * 64 + i]; sq += psumsq[t * 64 + i]; }
    float mean = s * (1.0f / 32768.0f);
    float var = sq * (1.0f / 32768.0f) - mean * mean;
    stats[t * 2] = mean;
    stats[t * 2 + 1] = rsqrtf(var + EPSV);
}

__global__ void gn_norm(const float* __restrict__ x, const float* __restrict__ stats,
                        const float* __restrict__ gs, const float* __restrict__ gb,
                        ushort* __restrict__ h) {
    size_t e = ((size_t)blockIdx.x * 256 + threadIdx.x) * 4;   // grid 8192
    int c = (int)(e & 255);
    int b = (int)(e >> 20);
    int g = c >> 3;
    float2 st = *(const float2*)&stats[(b * Gg + g) * 2];
    float4 v = *(const float4*)&x[e];
    float4 sc = *(const float4*)&gs[c];
    float4 bi = *(const float4*)&gb[c];
    ushort4 o;
    o.x = f2bf((v.x - st.x) * st.y * sc.x + bi.x);
    o.y = f2bf((v.y - st.x) * st.y * sc.y + bi.y);
    o.z = f2bf((v.z - st.x) * st.y * sc.z + bi.z);
    o.w = f2bf((v.w - st.x) * st.y * sc.w + bi.w);
    *(ushort4*)&h[e] = o;
}

// ---------------- fused QKV GEMM: read h once, produce q (log2-scaled), k, vT ----------------
__global__ __launch_bounds__(256) void qkv_fused(const ushort* __restrict__ h, const ushort* __restrict__ wT,
                                                 const float* __restrict__ bq, const float* __restrict__ bk,
                                                 const float* __restrict__ bv,
                                                 ushort* __restrict__ q, ushort* __restrict__ k,
                                                 ushort* __restrict__ vT) {
    int lane = threadIdx.x & 63, wvi = threadIdx.x >> 6;
    int lq = lane & 15, lg = lane >> 4;
    int m0 = blockIdx.x * 64 + wvi * 16;

    bf8_t a[8];
    const ushort* arow = h + (size_t)(m0 + lq) * 256 + lg * 8;
#pragma unroll
    for (int ks = 0; ks < 8; ++ks) a[ks] = *(const bf8_t*)(arow + ks * 32);

#pragma unroll
    for (int which = 0; which < 3; ++which) {
        const ushort* w = wT + which * 65536;
        const float* bias = which == 0 ? bq : which == 1 ? bk : bv;

        f4_t acc[16];
#pragma unroll
        for (int i = 0; i < 16; ++i) acc[i] = (f4_t)0.f;

        const ushort* brow = w + (size_t)lq * 256 + lg * 8;
#pragma unroll
        for (int nf = 0; nf < 16; ++nf) {
#pragma unroll
            for (int ks = 0; ks < 8; ++ks) {
                bf8_t bfr = *(const bf8_t*)(brow + nf * 16 * 256 + ks * 32);
                acc[nf] = __builtin_amdgcn_mfma_f32_16x16x32_bf16(a[ks], bfr, acc[nf], 0, 0, 0);
            }
        }
        if (which == 2) {
            // store transposed: vT[batch][d=col][hw]
            int bt = m0 >> 12;
            int hw0 = (m0 & 4095) + lg * 4;
#pragma unroll
            for (int nf = 0; nf < 16; ++nf) {
                int col = nf * 16 + lq;
                float bsv = bias[col];
                ushort4 pk;
                pk.x = f2bf(acc[nf][0] + bsv);
                pk.y = f2bf(acc[nf][1] + bsv);
                pk.z = f2bf(acc[nf][2] + bsv);
                pk.w = f2bf(acc[nf][3] + bsv);
                *(ushort4*)&vT[(size_t)bt * (256 * 4096) + (size_t)col * 4096 + hw0] = pk;
            }
        } else {
            ushort* out = which == 0 ? q : k;
            float scale = which == 0 ? QSCALE : 1.0f;
#pragma unroll
            for (int nf = 0; nf < 16; ++nf) {
                int col = nf * 16 + lq;
                float bsv = bias[col];
#pragma unroll
                for (int r = 0; r < 4; ++r) {
                    int row = m0 + lg * 4 + r;
                    out[(size_t)row * 256 + col] = f2bf((acc[nf][r] + bsv) * scale);
                }
            }
        }
    }
}

// ---------------- flash attention, split-KV x2, 8 waves, 160KB LDS ----------------
// 256 blocks: batch=bid&7 (XCD pinning), half=(bid>>3)&1, qt=bid>>4 (0..15). 8 waves x
// 32 q-rows = 256 q-rows/block; each block does 32 of 64 kv-tiles. K dbuf 2x32KB + Vt
// dbuf 2x32KB staged via global_load_lds (swizzled src); P per-wave 8x4KB. Softmax in
// exp2 domain (log2e folded into q). Counted vmcnt(8) keeps next tile's DMAs in flight.
__global__ __launch_bounds__(512, 2) void flash_kernel(const ushort* __restrict__ q,
                                                       const ushort* __restrict__ kk,
                                                       const ushort* __restrict__ vT,
                                                       ushort* __restrict__ Opart,
                                                       float* __restrict__ ml) {
    extern __shared__ char smem[];
    const int t = threadIdx.x, lane = t & 63, wvi = t >> 6;
    const int lq = lane & 15, lg = lane >> 4;
    const int bid = blockIdx.x;
    const int batch = bid & 7, half = (bid >> 3) & 1, qt = bid >> 4;
    const size_t bb = (size_t)batch * HW * Cc;
    const int t0 = half * 32;   // first kv tile

    // Q fragments for 2 q-subtiles (wave owns rows qbase..qbase+31)
    const int qbase = qt * 256 + wvi * 32;
    bf8_t qf0[8], qf1[8];
    {
        const ushort* qr0 = q + bb + (size_t)(qbase + lq) * Cc + lg * 8;
        const ushort* qr1 = qr0 + 16 * Cc;
#pragma unroll
        for (int ks = 0; ks < 8; ++ks) {
            qf0[ks] = *(const bf8_t*)(qr0 + ks * 32);
            qf1[ks] = *(const bf8_t*)(qr1 + ks * 32);
        }
    }

    f4_t o0[16], o1[16];
#pragma unroll
    for (int i = 0; i < 16; ++i) { o0[i] = (f4_t)0.f; o1[i] = (f4_t)0.f; }
    float m0 = -1e30f, l0 = 0.f, m1 = -1e30f, l1 = 0.f;

    char* Pb = smem + 131072 + wvi * 4096;   // P0 at +0 (2KB), P1 at +2048

    const ushort* ksrc_b = kk + bb;
    const ushort* vsrc_b = vT + (size_t)batch * (256 * 4096);
    const int tb = wvi * 64;

    auto stage = [&](int kt, int bufsel) {
        const ushort* ks_ = ksrc_b + (size_t)kt * 64 * 256;
        const ushort* vs_ = vsrc_b + kt * 64;
        char* kd = smem + bufsel * 32768;
        char* vd = smem + 65536 + bufsel * 32768;
        // K tile: 64 rows x 512B; LDS slot (kr, c') holds global chunk c = c' ^ (kr&7)
#pragma unroll
        for (int i = 0; i < 4; ++i) {
            int n = i * 512 + tb + lane;
            int kr = n >> 5;
            int c = (n & 31) ^ (kr & 7);
            gload16(ks_ + kr * 256 + c * 8, kd + (i * 512 + tb) * 16);
        }
        // Vt tile: 256 rows x 128B; slot (d, c') holds chunk c = c' ^ (d&7)
#pragma unroll
        for (int i = 0; i < 4; ++i) {
            int n = i * 512 + tb + lane;
            int d = n >> 3;
            int c = (n & 7) ^ (d & 7);
            gload16(vs_ + (size_t)d * HW + c * 8, vd + (i * 512 + tb) * 16);
        }
    };

    stage(t0, 0);

    for (int it = 0; it < 32; ++it) {
        const int cur = it & 1;
        const int kt = t0 + it;
        if (it + 1 < 32) {
            stage(kt + 1, cur ^ 1);
            asm volatile("s_waitcnt vmcnt(8)" ::: "memory");   // current tile's 8 DMAs done
        } else {
            asm volatile("s_waitcnt vmcnt(0)" ::: "memory");
        }
        __builtin_amdgcn_s_barrier();
        __builtin_amdgcn_sched_barrier(0);

        const char* Kb = smem + cur * 32768;
        const char* Vb = smem + 65536 + cur * 32768;

        // QK^T (swapped): sa[mf][r] = S^T[k = mf*16+lg*4+r][q-col = lq], log2 domain
        f4_t sa0[4], sa1[4];
#pragma unroll
        for (int mf = 0; mf < 4; ++mf) { sa0[mf] = (f4_t)0.f; sa1[mf] = (f4_t)0.f; }
        __builtin_amdgcn_s_setprio(1);
#pragma unroll
        for (int ks = 0; ks < 8; ++ks) {
#pragma unroll
            for (int mf = 0; mf < 4; ++mf) {
                int kr = mf * 16 + lq;
                bf8_t kf = *(const bf8_t*)(Kb + kr * 512 + (((ks * 4 + lg) ^ (kr & 7)) * 16));
                sa0[mf] = __builtin_amdgcn_mfma_f32_16x16x32_bf16(kf, qf0[ks], sa0[mf], 0, 0, 0);
                sa1[mf] = __builtin_amdgcn_mfma_f32_16x16x32_bf16(kf, qf1[ks], sa1[mf], 0, 0, 0);
            }
        }
        __builtin_amdgcn_s_setprio(0);

        // ---- online softmax (exp2 domain) with defer-max, qtile0 ----
        {
            float tmax = -1e30f;
#pragma unroll
            for (int mf = 0; mf < 4; ++mf)
#pragma unroll
                for (int r = 0; r < 4; ++r) tmax = fmaxf(tmax, sa0[mf][r]);
            tmax = fmaxf(tmax, __shfl_xor(tmax, 16));
            tmax = fmaxf(tmax, __shfl_xor(tmax, 32));
            if (!__all(tmax <= m0 + 8.0f)) {
                float mn = fmaxf(m0, tmax);
                float al = exp2f(m0 - mn);
                l0 *= al; m0 = mn;
                float ar[4];
#pragma unroll
                for (int r = 0; r < 4; ++r) ar[r] = __shfl(al, lg * 4 + r);
#pragma unroll
                for (int nf = 0; nf < 16; ++nf)
#pragma unroll
                    for (int r = 0; r < 4; ++r) o0[nf][r] *= ar[r];
            }
            float ts = 0.f;
#pragma unroll
            for (int mf = 0; mf < 4; ++mf)
#pragma unroll
                for (int r = 0; r < 4; ++r) { float p = exp2f(sa0[mf][r] - m0); sa0[mf][r] = p; ts += p; }
            ts += __shfl_xor(ts, 16);
            ts += __shfl_xor(ts, 32);
            l0 += ts;
#pragma unroll
            for (int mf = 0; mf < 4; ++mf)
#pragma unroll
                for (int rp = 0; rp < 2; ++rp) {
                    uint32_t pk = (uint32_t)f2bf(sa0[mf][rp * 2]) | ((uint32_t)f2bf(sa0[mf][rp * 2 + 1]) << 16);
                    int kx = mf * 16 + lg * 4 + rp * 2;
                    *(uint32_t*)(Pb + lq * 128 + (((kx >> 3) ^ (lq & 7)) * 16) + (kx & 7) * 2) = pk;
                }
        }
        // ---- online softmax (exp2 domain) with defer-max, qtile1 ----
        {
            float tmax = -1e30f;
#pragma unroll
            for (int mf = 0; mf < 4; ++mf)
#pragma unroll
                for (int r = 0; r < 4; ++r) tmax = fmaxf(tmax, sa1[mf][r]);
            tmax = fmaxf(tmax, __shfl_xor(tmax, 16));
            tmax = fmaxf(tmax, __shfl_xor(tmax, 32));
            if (!__all(tmax <= m1 + 8.0f)) {
                float mn = fmaxf(m1, tmax);
                float al = exp2f(m1 - mn);
                l1 *= al; m1 = mn;
                float ar[4];
#pragma unroll
                for (int r = 0; r < 4; ++r) ar[r] = __shfl(al, lg * 4 + r);
#pragma unroll
                for (int nf = 0; nf < 16; ++nf)
#pragma unroll
                    for (int r = 0; r < 4; ++r) o1[nf][r] *= ar[r];
            }
            float ts = 0.f;
#pragma unroll
            for (int mf = 0; mf < 4; ++mf)
#pragma unroll
                for (int r = 0; r < 4; ++r) { float p = exp2f(sa1[mf][r] - m1); sa1[mf][r] = p; ts += p; }
            ts += __shfl_xor(ts, 16);
            ts += __shfl_xor(ts, 32);
            l1 += ts;
#pragma unroll
            for (int mf = 0; mf < 4; ++mf)
#pragma unroll
                for (int rp = 0; rp < 2; ++rp) {
                    uint32_t pk = (uint32_t)f2bf(sa1[mf][rp * 2]) | ((uint32_t)f2bf(sa1[mf][rp * 2 + 1]) << 16);
                    int kx = mf * 16 + lg * 4 + rp * 2;
                    *(uint32_t*)(Pb + 2048 + lq * 128 + (((kx >> 3) ^ (lq & 7)) * 16) + (kx & 7) * 2) = pk;
                }
        }

        // PV: o += P @ V  (A = P from per-wave LDS, B = Vt fragments from LDS, shared)
        __builtin_amdgcn_s_setprio(1);
#pragma unroll
        for (int ks2 = 0; ks2 < 2; ++ks2) {
            int chunk = ks2 * 4 + lg;
            bf8_t pf0 = *(const bf8_t*)(Pb + lq * 128 + ((chunk ^ (lq & 7)) * 16));
            bf8_t pf1 = *(const bf8_t*)(Pb + 2048 + lq * 128 + ((chunk ^ (lq & 7)) * 16));
#pragma unroll
            for (int nf = 0; nf < 16; ++nf) {
                int d = nf * 16 + lq;
                bf8_t vf = *(const bf8_t*)(Vb + d * 128 + ((chunk ^ (d & 7)) * 16));
                o0[nf] = __builtin_amdgcn_mfma_f32_16x16x32_bf16(pf0, vf, o0[nf], 0, 0, 0);
                o1[nf] = __builtin_amdgcn_mfma_f32_16x16x32_bf16(pf1, vf, o1[nf], 0, 0, 0);
            }
        }
        __builtin_amdgcn_s_setprio(0);
        __syncthreads();   // all reads of buf cur done before it is restaged next iter
    }

    // epilogue: normalize by local l, store bf16 partial + (m,l) per row (m in log2 units)
    float i0[4], i1[4];
#pragma unroll
    for (int r = 0; r < 4; ++r) {
        i0[r] = 1.0f / __shfl(l0, lg * 4 + r);
        i1[r] = 1.0f / __shfl(l1, lg * 4 + r);
    }
    ushort* op = Opart + (size_t)bid * (256 * 256) + (size_t)(wvi * 32) * 256;
#pragma unroll
    for (int nf = 0; nf < 16; ++nf) {
        int col = nf * 16 + lq;
#pragma unroll
        for (int r = 0; r < 4; ++r) {
            op[(size_t)(lg * 4 + r) * 256 + col] = f2bf(o0[nf][r] * i0[r]);
            op[(size_t)(16 + lg * 4 + r) * 256 + col] = f2bf(o1[nf][r] * i1[r]);
        }
    }
    if (lg == 0) {
        float2* mlp = (float2*)(ml + (size_t)(bid * 256 + wvi * 32) * 2);
        mlp[lq] = make_float2(m0, l0);
        mlp[16 + lq] = make_float2(m1, l1);
    }
}

// ---------------- fused combine + proj GEMM + bias + residual (fp32 out) ----------------
// grid 512 x 256thr; wave owns 16 output rows. A-fragments are built on the fly by
// merging the two split-KV partials with their (m,l) weights (exp2 domain).
__global__ __launch_bounds__(256) void projc_gemm(const ushort* __restrict__ Opart,
                                                  const float* __restrict__ ml,
                                                  const ushort* __restrict__ wT,
                                                  const float* __restrict__ bp,
                                                  const float* __restrict__ x,
                                                  float* __restrict__ outp) {
    int lane = threadIdx.x & 63, wvi = threadIdx.x >> 6;
    int lq = lane & 15, lg = lane >> 4;
    int m0 = blockIdx.x * 64 + wvi * 16;

    int row = m0 + lq;
    int batch = row >> 12, rr = row & 4095;
    int qt = rr >> 8, rit = rr & 255;
    int blkA = batch + 16 * qt, blkB = blkA + 8;

    float2 mla = *(const float2*)&ml[(size_t)(blkA * 256 + rit) * 2];
    float2 mlb = *(const float2*)&ml[(size_t)(blkB * 256 + rit) * 2];
    float M = fmaxf(mla.x, mlb.x);
    float ea = exp2f(mla.x - M) * mla.y;
    float eb = exp2f(mlb.x - M) * mlb.y;
    float inv = 1.0f / (ea + eb);
    float wa = ea * inv, wb = eb * inv;

    const ushort* Arow = Opart + (size_t)blkA * 65536 + (size_t)rit * 256 + lg * 8;
    const ushort* Brow = Opart + (size_t)blkB * 65536 + (size_t)rit * 256 + lg * 8;

    bf8_t a[8];
#pragma unroll
    for (int ks = 0; ks < 8; ++ks) {
        bf8_t fa = *(const bf8_t*)(Arow + ks * 32);
        bf8_t fb = *(const bf8_t*)(Brow + ks * 32);
        bf8_t mg;
#pragma unroll
        for (int j = 0; j < 8; ++j)
            mg[j] = (short)f2bf(wa * bf2f((ushort)fa[j]) + wb * bf2f((ushort)fb[j]));
        a[ks] = mg;
    }

    f4_t acc[16];
#pragma unroll
    for (int i = 0; i < 16; ++i) acc[i] = (f4_t)0.f;

    const ushort* brow = wT + (size_t)lq * 256 + lg * 8;
#pragma unroll
    for (int nf = 0; nf < 16; ++nf) {
#pragma unroll
        for (int ks = 0; ks < 8; ++ks) {
            bf8_t bfr = *(const bf8_t*)(brow + nf * 16 * 256 + ks * 32);
            acc[nf] = __builtin_amdgcn_mfma_f32_16x16x32_bf16(a[ks], bfr, acc[nf], 0, 0, 0);
        }
    }
#pragma unroll
    for (int nf = 0; nf < 16; ++nf) {
        int col = nf * 16 + lq;
        float bsv = bp[col];
#pragma unroll
        for (int r = 0; r < 4; ++r) {
            size_t idx = (size_t)(m0 + lg * 4 + r) * 256 + col;
            outp[idx] = x[idx] + acc[nf][r] + bsv;
        }
    }
}

extern "C" void kernel_launch(void* const* d_in, const int* in_sizes, int n_in,
                              void* d_out, int out_size, void* d_ws, size_t ws_size,
                              hipStream_t stream) {
    const float* x  = (const float*)d_in[0];
    const float* gs = (const float*)d_in[1];
    const float* gb = (const float*)d_in[2];
    const float* wq = (const float*)d_in[3];
    const float* bq = (const float*)d_in[4];
    const float* wk = (const float*)d_in[5];
    const float* bk = (const float*)d_in[6];
    const float* wv = (const float*)d_in[7];
    const float* bv = (const float*)d_in[8];
    const float* wp = (const float*)d_in[9];
    const float* bp = (const float*)d_in[10];
    float* out = (float*)d_out;

    char* ws = (char*)d_ws;
    ushort* wT    = (ushort*)ws;                         // 512 KB
    float*  psum  = (float*)(ws + 512 * 1024);           // 64 KB
    float*  psumsq= (float*)(ws + 576 * 1024);           // 64 KB
    float*  stats = (float*)(ws + 640 * 1024);           // 2 KB
    ushort* h     = (ushort*)(ws + (1 << 20));           // 16 MB (GN output)
    ushort* qb    = (ushort*)(ws + (size_t)17 * (1 << 20));
    ushort* kb    = (ushort*)(ws + (size_t)33 * (1 << 20));
    ushort* vTb   = (ushort*)(ws + (size_t)49 * (1 << 20));   // V transposed [b][d][hw]
    ushort* Opart = (ushort*)(ws + (size_t)65 * (1 << 20));   // 32 MB: 256 x 256 x 256 bf16
    float*  mlb   = (float*)(ws + (size_t)97 * (1 << 20));    // 512 KB: 256 x 256 x float2

    wconv_kernel<<<dim3(256, 4), 256, 0, stream>>>(wq, wk, wv, wp, wT);
    gn_partial<<<dim3(64, 8), 256, 0, stream>>>(x, psum, psumsq);
    gn_stats<<<1, 256, 0, stream>>>(psum, psumsq, stats);
    gn_norm<<<8192, 256, 0, stream>>>(x, stats, gs, gb, h);
    qkv_fused<<<512, 256, 0, stream>>>(h, wT, bq, bk, bv, qb, kb, vTb);

    hipFuncSetAttribute(reinterpret_cast<const void*>(flash_kernel),
                        hipFuncAttributeMaxDynamicSharedMemorySize, 163840);
    flash_kernel<<<256, 512, 163840, stream>>>(qb, kb, vTb, Opart, mlb);

    projc_gemm<<<512, 256, 0, stream>>>(Opart, mlb, wT + 3 * 65536, bp, x, out);
}

// Round 7
// 334.341 us; speedup vs baseline: 1.8621x; 1.0948x over previous
//
#include <hip/hip_runtime.h>
#include <hip/hip_bf16.h>
#include <stdint.h>

// ---- problem constants ----
static constexpr int HW = 4096;     // 64*64
static constexpr int Cc = 256;
static constexpr int Gg = 32;
static constexpr float EPSV = 1e-6f;
static constexpr float QSCALE = 0.0625f * 1.44269504f;   // c^-0.5 * log2(e): softmax in exp2 domain

typedef __attribute__((ext_vector_type(8))) short bf8_t;     // 8 bf16 (4 VGPR)
typedef __attribute__((ext_vector_type(4))) float f4_t;      // 16x16 mfma acc
typedef __attribute__((ext_vector_type(16))) float f32x16;   // 32x32 mfma acc

__device__ __forceinline__ ushort f2bf(float x) {
    union { float f; uint32_t u; } v; v.f = x;
    uint32_t r = v.u + 0x7FFFu + ((v.u >> 16) & 1u);
    return (ushort)(r >> 16);
}
__device__ __forceinline__ float bf2f(ushort u) {
    union { uint32_t u; float f; } v; v.u = ((uint32_t)u) << 16;
    return v.f;
}
__device__ __forceinline__ uint32_t cvtpk(float lo, float hi_) {
    uint32_t r;
    asm volatile("v_cvt_pk_bf16_f32 %0, %1, %2" : "=v"(r) : "v"(lo), "v"(hi_));
    return r;
}

// async global->LDS DMA, 16B per lane; lds dest is wave-uniform base (+lane*16 by HW)
__device__ __forceinline__ void gload16(const void* g, void* l) {
    __builtin_amdgcn_global_load_lds((const __attribute__((address_space(1))) void*)g,
                                     (__attribute__((address_space(3))) void*)l, 16, 0, 0);
}

// ---------------- weight convert + transpose: wT[which][d][c] = bf16(w[c][d]) ----------------
__global__ void wconv_kernel(const float* __restrict__ wq, const float* __restrict__ wk,
                             const float* __restrict__ wv, const float* __restrict__ wp,
                             ushort* __restrict__ wT) {
    const float* w = (blockIdx.y == 0) ? wq : (blockIdx.y == 1) ? wk : (blockIdx.y == 2) ? wv : wp;
    int idx = blockIdx.x * 256 + threadIdx.x;        // 65536 total
    int d = idx >> 8, c = idx & 255;
    wT[blockIdx.y * 65536 + d * 256 + c] = f2bf(w[c * 256 + d]);
}

// ---------------- GroupNorm ----------------
__global__ void gn_partial(const float* __restrict__ x, float* __restrict__ psum, float* __restrict__ psumsq) {
    int slice = blockIdx.x;   // 64
    int b = blockIdx.y;       // 8
    int c = threadIdx.x;      // 256
    const float* xp = x + ((size_t)b * HW + (size_t)slice * 64) * Cc + c;
    float s = 0.f, sq = 0.f;
    for (int p = 0; p < 64; ++p) { float v = xp[(size_t)p * Cc]; s += v; sq += v * v; }
    for (int m = 1; m < 8; m <<= 1) { s += __shfl_xor(s, m); sq += __shfl_xor(sq, m); }
    if ((c & 7) == 0) {
        int g = c >> 3;
        psum[(b * Gg + g) * 64 + slice] = s;
        psumsq[(b * Gg + g) * 64 + slice] = sq;
    }
}

__global__ void gn_stats(const float* __restrict__ psum, const float* __restrict__ psumsq,
                         float* __restrict__ stats) {
    int t = threadIdx.x;  // 256 = b*32+g
    float s = 0.f, sq = 0.f;
    for (int i = 0; i < 64; ++i) { s += psum[t * 64 + i]; sq += psumsq[t * 64 + i]; }
    float mean = s * (1.0f / 32768.0f);
    float var = sq * (1.0f / 32768.0f) - mean * mean;
    stats[t * 2] = mean;
    stats[t * 2 + 1] = rsqrtf(var + EPSV);
}

__global__ void gn_norm(const float* __restrict__ x, const float* __restrict__ stats,
                        const float* __restrict__ gs, const float* __restrict__ gb,
                        ushort* __restrict__ h) {
    size_t e = ((size_t)blockIdx.x * 256 + threadIdx.x) * 4;   // grid 8192
    int c = (int)(e & 255);
    int b = (int)(e >> 20);
    int g = c >> 3;
    float2 st = *(const float2*)&stats[(b * Gg + g) * 2];
    float4 v = *(const float4*)&x[e];
    float4 sc = *(const float4*)&gs[c];
    float4 bi = *(const float4*)&gb[c];
    ushort4 o;
    o.x = f2bf((v.x - st.x) * st.y * sc.x + bi.x);
    o.y = f2bf((v.y - st.x) * st.y * sc.y + bi.y);
    o.z = f2bf((v.z - st.x) * st.y * sc.z + bi.z);
    o.w = f2bf((v.w - st.x) * st.y * sc.w + bi.w);
    *(ushort4*)&h[e] = o;
}

// ---------------- fused QKV GEMM: read h once, produce q (log2-scaled), k, vT ----------------
__global__ __launch_bounds__(256) void qkv_fused(const ushort* __restrict__ h, const ushort* __restrict__ wT,
                                                 const float* __restrict__ bq, const float* __restrict__ bk,
                                                 const float* __restrict__ bv,
                                                 ushort* __restrict__ q, ushort* __restrict__ k,
                                                 ushort* __restrict__ vT) {
    int lane = threadIdx.x & 63, wvi = threadIdx.x >> 6;
    int lq = lane & 15, lg = lane >> 4;
    int m0 = blockIdx.x * 64 + wvi * 16;

    bf8_t a[8];
    const ushort* arow = h + (size_t)(m0 + lq) * 256 + lg * 8;
#pragma unroll
    for (int ks = 0; ks < 8; ++ks) a[ks] = *(const bf8_t*)(arow + ks * 32);

#pragma unroll
    for (int which = 0; which < 3; ++which) {
        const ushort* w = wT + which * 65536;
        const float* bias = which == 0 ? bq : which == 1 ? bk : bv;

        f4_t acc[16];
#pragma unroll
        for (int i = 0; i < 16; ++i) acc[i] = (f4_t)0.f;

        const ushort* brow = w + (size_t)lq * 256 + lg * 8;
#pragma unroll
        for (int nf = 0; nf < 16; ++nf) {
#pragma unroll
            for (int ks = 0; ks < 8; ++ks) {
                bf8_t bfr = *(const bf8_t*)(brow + nf * 16 * 256 + ks * 32);
                acc[nf] = __builtin_amdgcn_mfma_f32_16x16x32_bf16(a[ks], bfr, acc[nf], 0, 0, 0);
            }
        }
        if (which == 2) {
            // store transposed: vT[batch][d=col][hw]
            int bt = m0 >> 12;
            int hw0 = (m0 & 4095) + lg * 4;
#pragma unroll
            for (int nf = 0; nf < 16; ++nf) {
                int col = nf * 16 + lq;
                float bsv = bias[col];
                ushort4 pk;
                pk.x = f2bf(acc[nf][0] + bsv);
                pk.y = f2bf(acc[nf][1] + bsv);
                pk.z = f2bf(acc[nf][2] + bsv);
                pk.w = f2bf(acc[nf][3] + bsv);
                *(ushort4*)&vT[(size_t)bt * (256 * 4096) + (size_t)col * 4096 + hw0] = pk;
            }
        } else {
            ushort* out = which == 0 ? q : k;
            float scale = which == 0 ? QSCALE : 1.0f;
#pragma unroll
            for (int nf = 0; nf < 16; ++nf) {
                int col = nf * 16 + lq;
                float bsv = bias[col];
#pragma unroll
                for (int r = 0; r < 4; ++r) {
                    int row = m0 + lg * 4 + r;
                    out[(size_t)row * 256 + col] = f2bf((acc[nf][r] + bsv) * scale);
                }
            }
        }
    }
}

// ---------------- flash attention: 32x32 MFMA, in-register softmax, split-KV x2 ----------------
// 256 blocks: batch=bid&7 (XCD pinning), half=(bid>>3)&1, qt=bid>>4. 8 waves x 32 q-rows.
// Swapped QK^T via mfma_32x32x16(K, Q): lane holds S^T[.][q=lane&31]; with partner lane^32
// covering the other kv rows, softmax is in-lane + 2 shfl_xor(32). P -> bf16 A-fragments via
// v_cvt_pk_bf16_f32 + v_permlane32_swap_b32 (no LDS round-trip). K dbuf 2x32KB + Vt dbuf
// 2x32KB (global_load_lds, XOR-swizzled sources). LDS = 128KB -> 1 block/CU, 2 waves/SIMD.
__global__ __launch_bounds__(512, 2) void flash_kernel(const ushort* __restrict__ q,
                                                       const ushort* __restrict__ kk,
                                                       const ushort* __restrict__ vT,
                                                       ushort* __restrict__ Opart,
                                                       float* __restrict__ ml) {
    extern __shared__ char smem[];
    const int t = threadIdx.x, lane = t & 63, wvi = t >> 6;
    const int l31 = lane & 31, hi = lane >> 5;
    const int bid = blockIdx.x;
    const int batch = bid & 7, half = (bid >> 3) & 1, qt = bid >> 4;
    const size_t bb = (size_t)batch * HW * Cc;
    const int t0 = half * 32;   // first kv tile

    // Q B-fragments: lane provides q-col = l31, k elems 16ks+8hi..+8  (16 frags = 64 VGPR)
    const int qbase = qt * 256 + wvi * 32;
    bf8_t qf[16];
    {
        const ushort* qrow = q + bb + (size_t)(qbase + l31) * Cc + hi * 8;
#pragma unroll
        for (int ks = 0; ks < 16; ++ks) qf[ks] = *(const bf8_t*)(qrow + ks * 16);
    }

    f32x16 o[8];
#pragma unroll
    for (int i = 0; i < 8; ++i) o[i] = (f32x16)0.f;
    float m_i = -1e30f, l_i = 0.f;

    const ushort* ksrc_b = kk + bb;
    const ushort* vsrc_b = vT + (size_t)batch * (256 * 4096);
    const int tb = wvi * 64;

    auto stage = [&](int kt, int bufsel) {
        const ushort* ks_ = ksrc_b + (size_t)kt * 64 * 256;
        const ushort* vs_ = vsrc_b + kt * 64;
        char* kd = smem + bufsel * 32768;
        char* vd = smem + 65536 + bufsel * 32768;
        // K tile: 64 rows x 512B; LDS slot (kr, c') holds global chunk c = c' ^ (kr&7)
#pragma unroll
        for (int i = 0; i < 4; ++i) {
            int n = i * 512 + tb + lane;
            int kr = n >> 5;
            int c = (n & 31) ^ (kr & 7);
            gload16(ks_ + kr * 256 + c * 8, kd + (i * 512 + tb) * 16);
        }
        // Vt tile: 256 rows x 128B; slot (d, c') holds chunk c = c' ^ (d&7)
#pragma unroll
        for (int i = 0; i < 4; ++i) {
            int n = i * 512 + tb + lane;
            int d = n >> 3;
            int c = (n & 7) ^ (d & 7);
            gload16(vs_ + (size_t)d * HW + c * 8, vd + (i * 512 + tb) * 16);
        }
    };

    stage(t0, 0);

    for (int it = 0; it < 32; ++it) {
        const int cur = it & 1;
        const int kt = t0 + it;
        if (it + 1 < 32) {
            stage(kt + 1, cur ^ 1);
            asm volatile("s_waitcnt vmcnt(8)" ::: "memory");   // current tile's 8 DMAs done
        } else {
            asm volatile("s_waitcnt vmcnt(0)" ::: "memory");
        }
        __builtin_amdgcn_s_barrier();
        __builtin_amdgcn_sched_barrier(0);

        const char* Kb = smem + cur * 32768;
        const char* Vb = smem + 65536 + cur * 32768;

        // QK^T (swapped, 32x32x16): sa0 = S^T[kv 0..31][q], sa1 = S^T[kv 32..63][q]
        f32x16 sa0 = (f32x16)0.f, sa1 = (f32x16)0.f;
        __builtin_amdgcn_s_setprio(1);
#pragma unroll
        for (int ks = 0; ks < 16; ++ks) {
            int chunk = 2 * ks + hi;
            int sw = (chunk ^ (l31 & 7)) * 16;
            bf8_t kf0 = *(const bf8_t*)(Kb + l31 * 512 + sw);
            bf8_t kf1 = *(const bf8_t*)(Kb + (32 + l31) * 512 + sw);
            sa0 = __builtin_amdgcn_mfma_f32_32x32x16_bf16(kf0, qf[ks], sa0, 0, 0, 0);
            sa1 = __builtin_amdgcn_mfma_f32_32x32x16_bf16(kf1, qf[ks], sa1, 0, 0, 0);
        }
        __builtin_amdgcn_s_setprio(0);

        // ---- in-register online softmax (exp2 domain), q-row = l31 ----
        float tmax = -1e30f;
#pragma unroll
        for (int r = 0; r < 16; ++r) tmax = fmaxf(tmax, fmaxf(sa0[r], sa1[r]));
        tmax = fmaxf(tmax, __shfl_xor(tmax, 32));
        if (!__all(tmax <= m_i + 8.0f)) {
            float mn = fmaxf(m_i, tmax);
            float al = exp2f(m_i - mn);
            l_i *= al; m_i = mn;
            float ar[16];
#pragma unroll
            for (int r = 0; r < 16; ++r) ar[r] = __shfl(al, (r & 3) + 8 * (r >> 2) + 4 * hi);
#pragma unroll
            for (int nt = 0; nt < 8; ++nt)
#pragma unroll
                for (int r = 0; r < 16; ++r) o[nt][r] *= ar[r];
        }
        float ts = 0.f;
#pragma unroll
        for (int r = 0; r < 16; ++r) { float p = exp2f(sa0[r] - m_i); sa0[r] = p; ts += p; }
#pragma unroll
        for (int r = 0; r < 16; ++r) { float p = exp2f(sa1[r] - m_i); sa1[r] = p; ts += p; }
        ts += __shfl_xor(ts, 32);
        l_i += ts;

        // ---- P -> bf16 A-fragments (cvt_pk + permlane32_swap) + PV per kv-slice ----
#pragma unroll
        for (int s = 0; s < 4; ++s) {
            int b8 = (s & 1) * 8;
            uint32_t w0, w1, w2, w3;
            if (s < 2) {
                w0 = cvtpk(sa0[b8 + 0], sa0[b8 + 1]);
                w1 = cvtpk(sa0[b8 + 2], sa0[b8 + 3]);
                w2 = cvtpk(sa0[b8 + 4], sa0[b8 + 5]);
                w3 = cvtpk(sa0[b8 + 6], sa0[b8 + 7]);
            } else {
                w0 = cvtpk(sa1[b8 + 0], sa1[b8 + 1]);
                w1 = cvtpk(sa1[b8 + 2], sa1[b8 + 3]);
                w2 = cvtpk(sa1[b8 + 4], sa1[b8 + 5]);
                w3 = cvtpk(sa1[b8 + 6], sa1[b8 + 7]);
            }
            asm volatile("v_permlane32_swap_b32 %0, %1" : "+v"(w0), "+v"(w2));
            asm volatile("v_permlane32_swap_b32 %0, %1" : "+v"(w1), "+v"(w3));
            union { uint32_t u[4]; bf8_t v; } pa;
            pa.u[0] = w0; pa.u[1] = w1; pa.u[2] = w2; pa.u[3] = w3;

            __builtin_amdgcn_s_setprio(1);
#pragma unroll
            for (int nt = 0; nt < 8; ++nt) {
                int d = nt * 32 + l31;
                int ch = 2 * s + hi;
                bf8_t vf = *(const bf8_t*)(Vb + d * 128 + ((ch ^ (d & 7)) * 16));
                o[nt] = __builtin_amdgcn_mfma_f32_32x32x16_bf16(pa.v, vf, o[nt], 0, 0, 0);
            }
            __builtin_amdgcn_s_setprio(0);
        }
        __syncthreads();   // all reads of buf cur done before it is restaged next iter
    }

    // epilogue: normalize by local l, store bf16 partial + (m,l) per row (m in log2 units)
    float linv = 1.0f / l_i;
    float ir[16];
#pragma unroll
    for (int r = 0; r < 16; ++r) ir[r] = __shfl(linv, (r & 3) + 8 * (r >> 2) + 4 * hi);
    ushort* op = Opart + (size_t)bid * (256 * 256) + (size_t)(wvi * 32) * 256;
#pragma unroll
    for (int nt = 0; nt < 8; ++nt) {
#pragma unroll
        for (int r = 0; r < 16; ++r) {
            int qrow = (r & 3) + 8 * (r >> 2) + 4 * hi;
            op[(size_t)qrow * 256 + nt * 32 + l31] = f2bf(o[nt][r] * ir[r]);
        }
    }
    if (lane < 32) {
        float2* mlp = (float2*)(ml + (size_t)(bid * 256 + wvi * 32) * 2);
        mlp[l31] = make_float2(m_i, l_i);
    }
}

// ---------------- fused combine + proj GEMM + bias + residual (fp32 out) ----------------
__global__ __launch_bounds__(256) void projc_gemm(const ushort* __restrict__ Opart,
                                                  const float* __restrict__ ml,
                                                  const ushort* __restrict__ wT,
                                                  const float* __restrict__ bp,
                                                  const float* __restrict__ x,
                                                  float* __restrict__ outp) {
    int lane = threadIdx.x & 63, wvi = threadIdx.x >> 6;
    int lq = lane & 15, lg = lane >> 4;
    int m0 = blockIdx.x * 64 + wvi * 16;

    int row = m0 + lq;
    int batch = row >> 12, rr = row & 4095;
    int qt = rr >> 8, rit = rr & 255;
    int blkA = batch + 16 * qt, blkB = blkA + 8;

    float2 mla = *(const float2*)&ml[(size_t)(blkA * 256 + rit) * 2];
    float2 mlb = *(const float2*)&ml[(size_t)(blkB * 256 + rit) * 2];
    float M = fmaxf(mla.x, mlb.x);
    float ea = exp2f(mla.x - M) * mla.y;
    float eb = exp2f(mlb.x - M) * mlb.y;
    float inv = 1.0f / (ea + eb);
    float wa = ea * inv, wb = eb * inv;

    const ushort* Arow = Opart + (size_t)blkA * 65536 + (size_t)rit * 256 + lg * 8;
    const ushort* Brow = Opart + (size_t)blkB * 65536 + (size_t)rit * 256 + lg * 8;

    bf8_t a[8];
#pragma unroll
    for (int ks = 0; ks < 8; ++ks) {
        bf8_t fa = *(const bf8_t*)(Arow + ks * 32);
        bf8_t fb = *(const bf8_t*)(Brow + ks * 32);
        bf8_t mg;
#pragma unroll
        for (int j = 0; j < 8; ++j)
            mg[j] = (short)f2bf(wa * bf2f((ushort)fa[j]) + wb * bf2f((ushort)fb[j]));
        a[ks] = mg;
    }

    f4_t acc[16];
#pragma unroll
    for (int i = 0; i < 16; ++i) acc[i] = (f4_t)0.f;

    const ushort* brow = wT + (size_t)lq * 256 + lg * 8;
#pragma unroll
    for (int nf = 0; nf < 16; ++nf) {
#pragma unroll
        for (int ks = 0; ks < 8; ++ks) {
            bf8_t bfr = *(const bf8_t*)(brow + nf * 16 * 256 + ks * 32);
            acc[nf] = __builtin_amdgcn_mfma_f32_16x16x32_bf16(a[ks], bfr, acc[nf], 0, 0, 0);
        }
    }
#pragma unroll
    for (int nf = 0; nf < 16; ++nf) {
        int col = nf * 16 + lq;
        float bsv = bp[col];
#pragma unroll
        for (int r = 0; r < 4; ++r) {
            size_t idx = (size_t)(m0 + lg * 4 + r) * 256 + col;
            outp[idx] = x[idx] + acc[nf][r] + bsv;
        }
    }
}

extern "C" void kernel_launch(void* const* d_in, const int* in_sizes, int n_in,
                              void* d_out, int out_size, void* d_ws, size_t ws_size,
                              hipStream_t stream) {
    const float* x  = (const float*)d_in[0];
    const float* gs = (const float*)d_in[1];
    const float* gb = (const float*)d_in[2];
    const float* wq = (const float*)d_in[3];
    const float* bq = (const float*)d_in[4];
    const float* wk = (const float*)d_in[5];
    const float* bk = (const float*)d_in[6];
    const float* wv = (const float*)d_in[7];
    const float* bv = (const float*)d_in[8];
    const float* wp = (const float*)d_in[9];
    const float* bp = (const float*)d_in[10];
    float* out = (float*)d_out;

    char* ws = (char*)d_ws;
    ushort* wT    = (ushort*)ws;                         // 512 KB
    float*  psum  = (float*)(ws + 512 * 1024);           // 64 KB
    float*  psumsq= (float*)(ws + 576 * 1024);           // 64 KB
    float*  stats = (float*)(ws + 640 * 1024);           // 2 KB
    ushort* h     = (ushort*)(ws + (1 << 20));           // 16 MB (GN output)
    ushort* qb    = (ushort*)(ws + (size_t)17 * (1 << 20));
    ushort* kb    = (ushort*)(ws + (size_t)33 * (1 << 20));
    ushort* vTb   = (ushort*)(ws + (size_t)49 * (1 << 20));   // V transposed [b][d][hw]
    ushort* Opart = (ushort*)(ws + (size_t)65 * (1 << 20));   // 32 MB: 256 x 256 x 256 bf16
    float*  mlb   = (float*)(ws + (size_t)97 * (1 << 20));    // 512 KB: 256 x 256 x float2

    wconv_kernel<<<dim3(256, 4), 256, 0, stream>>>(wq, wk, wv, wp, wT);
    gn_partial<<<dim3(64, 8), 256, 0, stream>>>(x, psum, psumsq);
    gn_stats<<<1, 256, 0, stream>>>(psum, psumsq, stats);
    gn_norm<<<8192, 256, 0, stream>>>(x, stats, gs, gb, h);
    qkv_fused<<<512, 256, 0, stream>>>(h, wT, bq, bk, bv, qb, kb, vTb);

    hipFuncSetAttribute(reinterpret_cast<const void*>(flash_kernel),
                        hipFuncAttributeMaxDynamicSharedMemorySize, 131072);
    flash_kernel<<<256, 512, 131072, stream>>>(qb, kb, vTb, Opart, mlb);

    projc_gemm<<<512, 256, 0, stream>>>(Opart, mlb, wT + 3 * 65536, bp, x, out);
}

// Round 8
// 330.158 us; speedup vs baseline: 1.8857x; 1.0127x over previous
//
#include <hip/hip_runtime.h>
#include <hip/hip_bf16.h>
#include <stdint.h>

// ---- problem constants ----
static constexpr int HW = 4096;     // 64*64
static constexpr int Cc = 256;
static constexpr int Gg = 32;
static constexpr float EPSV = 1e-6f;
static constexpr float QSCALE = 0.0625f * 1.44269504f;   // c^-0.5 * log2(e): softmax in exp2 domain

typedef __attribute__((ext_vector_type(8))) short bf8_t;     // 8 bf16 (4 VGPR)
typedef __attribute__((ext_vector_type(4))) float f4_t;      // 16x16 mfma acc
typedef __attribute__((ext_vector_type(16))) float f32x16;   // 32x32 mfma acc

__device__ __forceinline__ ushort f2bf(float x) {
    union { float f; uint32_t u; } v; v.f = x;
    uint32_t r = v.u + 0x7FFFu + ((v.u >> 16) & 1u);
    return (ushort)(r >> 16);
}
__device__ __forceinline__ float bf2f(ushort u) {
    union { uint32_t u; float f; } v; v.u = ((uint32_t)u) << 16;
    return v.f;
}
__device__ __forceinline__ uint32_t cvtpk(float lo, float hi_) {
    uint32_t r;
    asm volatile("v_cvt_pk_bf16_f32 %0, %1, %2" : "=v"(r) : "v"(lo), "v"(hi_));
    return r;
}

// async global->LDS DMA, 16B per lane; lds dest is wave-uniform base (+lane*16 by HW)
__device__ __forceinline__ void gload16(const void* g, void* l) {
    __builtin_amdgcn_global_load_lds((const __attribute__((address_space(1))) void*)g,
                                     (__attribute__((address_space(3))) void*)l, 16, 0, 0);
}

// ---------------- weight convert + transpose: wT[which][d][c] = bf16(w[c][d]) ----------------
__global__ void wconv_kernel(const float* __restrict__ wq, const float* __restrict__ wk,
                             const float* __restrict__ wv, const float* __restrict__ wp,
                             ushort* __restrict__ wT) {
    const float* w = (blockIdx.y == 0) ? wq : (blockIdx.y == 1) ? wk : (blockIdx.y == 2) ? wv : wp;
    int idx = blockIdx.x * 256 + threadIdx.x;        // 65536 total
    int d = idx >> 8, c = idx & 255;
    wT[blockIdx.y * 65536 + d * 256 + c] = f2bf(w[c * 256 + d]);
}

// ---------------- GroupNorm stats ----------------
__global__ void gn_partial(const float* __restrict__ x, float* __restrict__ psum, float* __restrict__ psumsq) {
    int slice = blockIdx.x;   // 64
    int b = blockIdx.y;       // 8
    int c = threadIdx.x;      // 256
    const float* xp = x + ((size_t)b * HW + (size_t)slice * 64) * Cc + c;
    float s = 0.f, sq = 0.f;
    for (int p = 0; p < 64; ++p) { float v = xp[(size_t)p * Cc]; s += v; sq += v * v; }
    for (int m = 1; m < 8; m <<= 1) { s += __shfl_xor(s, m); sq += __shfl_xor(sq, m); }
    if ((c & 7) == 0) {
        int g = c >> 3;
        psum[(b * Gg + g) * 64 + slice] = s;
        psumsq[(b * Gg + g) * 64 + slice] = sq;
    }
}

__global__ void gn_stats(const float* __restrict__ psum, const float* __restrict__ psumsq,
                         float* __restrict__ stats) {
    int t = threadIdx.x;  // 256 = b*32+g
    float s = 0.f, sq = 0.f;
    for (int i = 0; i < 64; ++i) { s += psum[t * 64 + i]; sq += psumsq[t * 64 + i]; }
    float mean = s * (1.0f / 32768.0f);
    float var = sq * (1.0f / 32768.0f) - mean * mean;
    stats[t * 2] = mean;
    stats[t * 2 + 1] = rsqrtf(var + EPSV);
}

// ---------------- fused GN-normalize + QKV GEMM ----------------
// Reads x (fp32) + stats directly, builds normalized bf16 A-fragments in registers,
// produces q (log2-scaled), k, vT. No h intermediate.
__global__ __launch_bounds__(256) void qkv_gn(const float* __restrict__ x, const float* __restrict__ stats,
                                              const float* __restrict__ gs, const float* __restrict__ gb,
                                              const ushort* __restrict__ wT,
                                              const float* __restrict__ bq, const float* __restrict__ bk,
                                              const float* __restrict__ bv,
                                              ushort* __restrict__ q, ushort* __restrict__ k,
                                              ushort* __restrict__ vT) {
    int lane = threadIdx.x & 63, wvi = threadIdx.x >> 6;
    int lq = lane & 15, lg = lane >> 4;
    int m0 = blockIdx.x * 64 + wvi * 16;
    int row = m0 + lq;
    int batch = row >> 12;

    bf8_t a[8];
    const float* xr = x + (size_t)row * 256;
#pragma unroll
    for (int ks = 0; ks < 8; ++ks) {
        int c0 = ks * 32 + lg * 8;
        int g = c0 >> 3;                       // 8 channels per group, c0 aligned to 8
        float2 st = *(const float2*)&stats[(batch * Gg + g) * 2];
        float4 v0 = *(const float4*)&xr[c0];
        float4 v1 = *(const float4*)&xr[c0 + 4];
        float4 s0 = *(const float4*)&gs[c0];
        float4 s1 = *(const float4*)&gs[c0 + 4];
        float4 b0 = *(const float4*)&gb[c0];
        float4 b1 = *(const float4*)&gb[c0 + 4];
        bf8_t fr;
        fr[0] = (short)f2bf((v0.x - st.x) * st.y * s0.x + b0.x);
        fr[1] = (short)f2bf((v0.y - st.x) * st.y * s0.y + b0.y);
        fr[2] = (short)f2bf((v0.z - st.x) * st.y * s0.z + b0.z);
        fr[3] = (short)f2bf((v0.w - st.x) * st.y * s0.w + b0.w);
        fr[4] = (short)f2bf((v1.x - st.x) * st.y * s1.x + b1.x);
        fr[5] = (short)f2bf((v1.y - st.x) * st.y * s1.y + b1.y);
        fr[6] = (short)f2bf((v1.z - st.x) * st.y * s1.z + b1.z);
        fr[7] = (short)f2bf((v1.w - st.x) * st.y * s1.w + b1.w);
        a[ks] = fr;
    }

#pragma unroll
    for (int which = 0; which < 3; ++which) {
        const ushort* w = wT + which * 65536;
        const float* bias = which == 0 ? bq : which == 1 ? bk : bv;

        f4_t acc[16];
#pragma unroll
        for (int i = 0; i < 16; ++i) acc[i] = (f4_t)0.f;

        const ushort* brow = w + (size_t)lq * 256 + lg * 8;
#pragma unroll
        for (int nf = 0; nf < 16; ++nf) {
#pragma unroll
            for (int ks = 0; ks < 8; ++ks) {
                bf8_t bfr = *(const bf8_t*)(brow + nf * 16 * 256 + ks * 32);
                acc[nf] = __builtin_amdgcn_mfma_f32_16x16x32_bf16(a[ks], bfr, acc[nf], 0, 0, 0);
            }
        }
        if (which == 2) {
            // store transposed: vT[batch][d=col][hw]
            int bt = m0 >> 12;
            int hw0 = (m0 & 4095) + lg * 4;
#pragma unroll
            for (int nf = 0; nf < 16; ++nf) {
                int col = nf * 16 + lq;
                float bsv = bias[col];
                ushort4 pk;
                pk.x = f2bf(acc[nf][0] + bsv);
                pk.y = f2bf(acc[nf][1] + bsv);
                pk.z = f2bf(acc[nf][2] + bsv);
                pk.w = f2bf(acc[nf][3] + bsv);
                *(ushort4*)&vT[(size_t)bt * (256 * 4096) + (size_t)col * 4096 + hw0] = pk;
            }
        } else {
            ushort* out = which == 0 ? q : k;
            float scale = which == 0 ? QSCALE : 1.0f;
#pragma unroll
            for (int nf = 0; nf < 16; ++nf) {
                int col = nf * 16 + lq;
                float bsv = bias[col];
#pragma unroll
                for (int r = 0; r < 4; ++r) {
                    int rr = m0 + lg * 4 + r;
                    out[(size_t)rr * 256 + col] = f2bf((acc[nf][r] + bsv) * scale);
                }
            }
        }
    }
}

// ---------------- flash attention: 32x32 MFMA, in-register softmax, split-KV x2 ----------------
// 256 blocks: batch=bid&7 (XCD pinning), half=(bid>>3)&1, qt=bid>>4. 8 waves x 32 q-rows.
// SINGLE barrier per kv-tile: stage(t+1) issued first, compute from cur, then
// vmcnt(0)+s_barrier at the end (DMA latency hides under compute; waves skew within tile).
// Swapped QK^T (mfma_32x32x16(K,Q)); softmax fully in-register (lane&31 = q-row);
// P->bf16 A-frags via v_cvt_pk_bf16_f32 + v_permlane32_swap_b32. LDS 128KB (K,V dbuf).
// Output: UNNORMALIZED O partial + (m,l); projc does the combine + 1/l.
__global__ __launch_bounds__(512, 2) void flash_kernel(const ushort* __restrict__ q,
                                                       const ushort* __restrict__ kk,
                                                       const ushort* __restrict__ vT,
                                                       ushort* __restrict__ Opart,
                                                       float* __restrict__ ml) {
    extern __shared__ char smem[];
    const int t = threadIdx.x, lane = t & 63, wvi = t >> 6;
    const int l31 = lane & 31, hi = lane >> 5;
    const int bid = blockIdx.x;
    const int batch = bid & 7, half = (bid >> 3) & 1, qt = bid >> 4;
    const size_t bb = (size_t)batch * HW * Cc;
    const int t0 = half * 32;   // first kv tile

    // Q B-fragments: lane provides q-col = l31, k elems 16ks+8hi..+8  (16 frags = 64 VGPR)
    const int qbase = qt * 256 + wvi * 32;
    bf8_t qf[16];
    {
        const ushort* qrow = q + bb + (size_t)(qbase + l31) * Cc + hi * 8;
#pragma unroll
        for (int ks = 0; ks < 16; ++ks) qf[ks] = *(const bf8_t*)(qrow + ks * 16);
    }

    f32x16 o[8];
#pragma unroll
    for (int i = 0; i < 8; ++i) o[i] = (f32x16)0.f;
    float m_i = -1e30f, l_i = 0.f;

    const ushort* ksrc_b = kk + bb;
    const ushort* vsrc_b = vT + (size_t)batch * (256 * 4096);
    const int tb = wvi * 64;

    auto stage = [&](int kt, int bufsel) {
        const ushort* ks_ = ksrc_b + (size_t)kt * 64 * 256;
        const ushort* vs_ = vsrc_b + kt * 64;
        char* kd = smem + bufsel * 32768;
        char* vd = smem + 65536 + bufsel * 32768;
        // K tile: 64 rows x 512B; LDS slot (kr, c') holds global chunk c = c' ^ (kr&7)
#pragma unroll
        for (int i = 0; i < 4; ++i) {
            int n = i * 512 + tb + lane;
            int kr = n >> 5;
            int c = (n & 31) ^ (kr & 7);
            gload16(ks_ + kr * 256 + c * 8, kd + (i * 512 + tb) * 16);
        }
        // Vt tile: 256 rows x 128B; slot (d, c') holds chunk c = c' ^ (d&7)
#pragma unroll
        for (int i = 0; i < 4; ++i) {
            int n = i * 512 + tb + lane;
            int d = n >> 3;
            int c = (n & 7) ^ (d & 7);
            gload16(vs_ + (size_t)d * HW + c * 8, vd + (i * 512 + tb) * 16);
        }
    };

    stage(t0, 0);
    asm volatile("s_waitcnt vmcnt(0)" ::: "memory");
    __builtin_amdgcn_s_barrier();
    __builtin_amdgcn_sched_barrier(0);

    for (int it = 0; it < 32; ++it) {
        const int cur = it & 1;
        if (it + 1 < 32) stage(t0 + it + 1, cur ^ 1);   // issue next tile's DMAs early

        const char* Kb = smem + cur * 32768;
        const char* Vb = smem + 65536 + cur * 32768;

        // QK^T (swapped, 32x32x16): sa0 = S^T[kv 0..31][q], sa1 = S^T[kv 32..63][q]
        f32x16 sa0 = (f32x16)0.f, sa1 = (f32x16)0.f;
        __builtin_amdgcn_s_setprio(1);
#pragma unroll
        for (int ks = 0; ks < 16; ++ks) {
            int chunk = 2 * ks + hi;
            int sw = (chunk ^ (l31 & 7)) * 16;
            bf8_t kf0 = *(const bf8_t*)(Kb + l31 * 512 + sw);
            bf8_t kf1 = *(const bf8_t*)(Kb + (32 + l31) * 512 + sw);
            sa0 = __builtin_amdgcn_mfma_f32_32x32x16_bf16(kf0, qf[ks], sa0, 0, 0, 0);
            sa1 = __builtin_amdgcn_mfma_f32_32x32x16_bf16(kf1, qf[ks], sa1, 0, 0, 0);
        }
        __builtin_amdgcn_s_setprio(0);

        // ---- in-register online softmax (exp2 domain), q-row = l31 ----
        float tmax = -1e30f;
#pragma unroll
        for (int r = 0; r < 16; ++r) tmax = fmaxf(tmax, fmaxf(sa0[r], sa1[r]));
        tmax = fmaxf(tmax, __shfl_xor(tmax, 32));
        if (!__all(tmax <= m_i + 8.0f)) {
            float mn = fmaxf(m_i, tmax);
            float al = exp2f(m_i - mn);
            l_i *= al; m_i = mn;
            float ar[16];
#pragma unroll
            for (int r = 0; r < 16; ++r) ar[r] = __shfl(al, (r & 3) + 8 * (r >> 2) + 4 * hi);
#pragma unroll
            for (int nt = 0; nt < 8; ++nt)
#pragma unroll
                for (int r = 0; r < 16; ++r) o[nt][r] *= ar[r];
        }
        float ts = 0.f;
#pragma unroll
        for (int r = 0; r < 16; ++r) { float p = exp2f(sa0[r] - m_i); sa0[r] = p; ts += p; }
#pragma unroll
        for (int r = 0; r < 16; ++r) { float p = exp2f(sa1[r] - m_i); sa1[r] = p; ts += p; }
        ts += __shfl_xor(ts, 32);
        l_i += ts;

        // ---- P -> bf16 A-fragments (cvt_pk + permlane32_swap) + PV per kv-slice ----
#pragma unroll
        for (int s = 0; s < 4; ++s) {
            int b8 = (s & 1) * 8;
            uint32_t w0, w1, w2, w3;
            if (s < 2) {
                w0 = cvtpk(sa0[b8 + 0], sa0[b8 + 1]);
                w1 = cvtpk(sa0[b8 + 2], sa0[b8 + 3]);
                w2 = cvtpk(sa0[b8 + 4], sa0[b8 + 5]);
                w3 = cvtpk(sa0[b8 + 6], sa0[b8 + 7]);
            } else {
                w0 = cvtpk(sa1[b8 + 0], sa1[b8 + 1]);
                w1 = cvtpk(sa1[b8 + 2], sa1[b8 + 3]);
                w2 = cvtpk(sa1[b8 + 4], sa1[b8 + 5]);
                w3 = cvtpk(sa1[b8 + 6], sa1[b8 + 7]);
            }
            asm volatile("v_permlane32_swap_b32 %0, %1" : "+v"(w0), "+v"(w2));
            asm volatile("v_permlane32_swap_b32 %0, %1" : "+v"(w1), "+v"(w3));
            union { uint32_t u[4]; bf8_t v; } pa;
            pa.u[0] = w0; pa.u[1] = w1; pa.u[2] = w2; pa.u[3] = w3;

            __builtin_amdgcn_s_setprio(1);
#pragma unroll
            for (int nt = 0; nt < 8; ++nt) {
                int d = nt * 32 + l31;
                int ch = 2 * s + hi;
                bf8_t vf = *(const bf8_t*)(Vb + d * 128 + ((ch ^ (d & 7)) * 16));
                o[nt] = __builtin_amdgcn_mfma_f32_32x32x16_bf16(pa.v, vf, o[nt], 0, 0, 0);
            }
            __builtin_amdgcn_s_setprio(0);
        }

        // single convergence point per tile: my next-tile DMAs done + everyone done reading cur
        if (it + 1 < 32) {
            asm volatile("s_waitcnt vmcnt(0)" ::: "memory");
            __builtin_amdgcn_s_barrier();
            __builtin_amdgcn_sched_barrier(0);
        }
    }

    // epilogue: store UNNORMALIZED bf16 partial + (m,l) per row (m in log2 units)
    ushort* op = Opart + (size_t)bid * (256 * 256) + (size_t)(wvi * 32) * 256;
#pragma unroll
    for (int nt = 0; nt < 8; ++nt) {
#pragma unroll
        for (int r = 0; r < 16; ++r) {
            int qrow = (r & 3) + 8 * (r >> 2) + 4 * hi;
            op[(size_t)qrow * 256 + nt * 32 + l31] = f2bf(o[nt][r]);
        }
    }
    if (lane < 32) {
        float2* mlp = (float2*)(ml + (size_t)(bid * 256 + wvi * 32) * 2);
        mlp[l31] = make_float2(m_i, l_i);
    }
}

// ---------------- fused combine + proj GEMM + bias + residual (fp32 out) ----------------
__global__ __launch_bounds__(256) void projc_gemm(const ushort* __restrict__ Opart,
                                                  const float* __restrict__ ml,
                                                  const ushort* __restrict__ wT,
                                                  const float* __restrict__ bp,
                                                  const float* __restrict__ x,
                                                  float* __restrict__ outp) {
    int lane = threadIdx.x & 63, wvi = threadIdx.x >> 6;
    int lq = lane & 15, lg = lane >> 4;
    int m0 = blockIdx.x * 64 + wvi * 16;

    int row = m0 + lq;
    int batch = row >> 12, rr = row & 4095;
    int qt = rr >> 8, rit = rr & 255;
    int blkA = batch + 16 * qt, blkB = blkA + 8;

    float2 mla = *(const float2*)&ml[(size_t)(blkA * 256 + rit) * 2];
    float2 mlb = *(const float2*)&ml[(size_t)(blkB * 256 + rit) * 2];
    float M = fmaxf(mla.x, mlb.x);
    float wa = exp2f(mla.x - M);
    float wb = exp2f(mlb.x - M);
    float inv = 1.0f / (wa * mla.y + wb * mlb.y);   // Opart is unnormalized: weight by exp2(m-M)/denom
    wa *= inv; wb *= inv;

    const ushort* Arow = Opart + (size_t)blkA * 65536 + (size_t)rit * 256 + lg * 8;
    const ushort* Brow = Opart + (size_t)blkB * 65536 + (size_t)rit * 256 + lg * 8;

    bf8_t a[8];
#pragma unroll
    for (int ks = 0; ks < 8; ++ks) {
        bf8_t fa = *(const bf8_t*)(Arow + ks * 32);
        bf8_t fb = *(const bf8_t*)(Brow + ks * 32);
        bf8_t mg;
#pragma unroll
        for (int j = 0; j < 8; ++j)
            mg[j] = (short)f2bf(wa * bf2f((ushort)fa[j]) + wb * bf2f((ushort)fb[j]));
        a[ks] = mg;
    }

    f4_t acc[16];
#pragma unroll
    for (int i = 0; i < 16; ++i) acc[i] = (f4_t)0.f;

    const ushort* brow = wT + (size_t)lq * 256 + lg * 8;
#pragma unroll
    for (int nf = 0; nf < 16; ++nf) {
#pragma unroll
        for (int ks = 0; ks < 8; ++ks) {
            bf8_t bfr = *(const bf8_t*)(brow + nf * 16 * 256 + ks * 32);
            acc[nf] = __builtin_amdgcn_mfma_f32_16x16x32_bf16(a[ks], bfr, acc[nf], 0, 0, 0);
        }
    }
#pragma unroll
    for (int nf = 0; nf < 16; ++nf) {
        int col = nf * 16 + lq;
        float bsv = bp[col];
#pragma unroll
        for (int r = 0; r < 4; ++r) {
            size_t idx = (size_t)(m0 + lg * 4 + r) * 256 + col;
            outp[idx] = x[idx] + acc[nf][r] + bsv;
        }
    }
}

extern "C" void kernel_launch(void* const* d_in, const int* in_sizes, int n_in,
                              void* d_out, int out_size, void* d_ws, size_t ws_size,
                              hipStream_t stream) {
    const float* x  = (const float*)d_in[0];
    const float* gs = (const float*)d_in[1];
    const float* gb = (const float*)d_in[2];
    const float* wq = (const float*)d_in[3];
    const float* bq = (const float*)d_in[4];
    const float* wk = (const float*)d_in[5];
    const float* bk = (const float*)d_in[6];
    const float* wv = (const float*)d_in[7];
    const float* bv = (const float*)d_in[8];
    const float* wp = (const float*)d_in[9];
    const float* bp = (const float*)d_in[10];
    float* out = (float*)d_out;

    char* ws = (char*)d_ws;
    ushort* wT    = (ushort*)ws;                         // 512 KB
    float*  psum  = (float*)(ws + 512 * 1024);           // 64 KB
    float*  psumsq= (float*)(ws + 576 * 1024);           // 64 KB
    float*  stats = (float*)(ws + 640 * 1024);           // 2 KB
    ushort* qb    = (ushort*)(ws + (size_t)17 * (1 << 20));
    ushort* kb    = (ushort*)(ws + (size_t)33 * (1 << 20));
    ushort* vTb   = (ushort*)(ws + (size_t)49 * (1 << 20));   // V transposed [b][d][hw]
    ushort* Opart = (ushort*)(ws + (size_t)65 * (1 << 20));   // 32 MB: 256 x 256 x 256 bf16
    float*  mlb   = (float*)(ws + (size_t)97 * (1 << 20));    // 512 KB: 256 x 256 x float2

    wconv_kernel<<<dim3(256, 4), 256, 0, stream>>>(wq, wk, wv, wp, wT);
    gn_partial<<<dim3(64, 8), 256, 0, stream>>>(x, psum, psumsq);
    gn_stats<<<1, 256, 0, stream>>>(psum, psumsq, stats);
    qkv_gn<<<512, 256, 0, stream>>>(x, stats, gs, gb, wT, bq, bk, bv, qb, kb, vTb);

    hipFuncSetAttribute(reinterpret_cast<const void*>(flash_kernel),
                        hipFuncAttributeMaxDynamicSharedMemorySize, 131072);
    flash_kernel<<<256, 512, 131072, stream>>>(qb, kb, vTb, Opart, mlb);

    projc_gemm<<<512, 256, 0, stream>>>(Opart, mlb, wT + 3 * 65536, bp, x, out);
}